// Round 2
// baseline (5942.225 us; speedup 1.0000x reference)
//
#include <hip/hip_runtime.h>
#include <cstdint>
#include <cstddef>

using u64 = unsigned long long;
using i64 = long long;

#define DEVI __device__ __forceinline__

// ---------------------------------------------------------------- reductions
DEVI double waveRed(double v) {
    #pragma unroll
    for (int o = 32; o > 0; o >>= 1) v += __shfl_down(v, o, 64);
    return v;
}

// ---------------------------------------------------------------- conv0 stats (np-f32: FMA chain, (kh,kw,ci) order)
__global__ __launch_bounds__(256, 1) void conv0_sums3(const float* __restrict__ x,
                                                      const float* __restrict__ w0,
                                                      double* __restrict__ sum,
                                                      double* __restrict__ sumsq) {
    __shared__ float xs[3072];
    __shared__ float wsh[864];          // 32 co * 27, tap-major
    __shared__ double redS[4][32], redS2[4][32];
    int tid = threadIdx.x, n = blockIdx.y, co0 = blockIdx.x * 32;
    for (int i = tid; i < 3072; i += 256) xs[i] = x[n * 3072 + i];
    for (int i = tid; i < 864; i += 256) {
        int co = i / 27, j = i % 27;    // j = tap-major (kh*3+kw)*3 + ci
        int ci = j % 3, k = j / 3;
        wsh[i] = w0[(co0 + co) * 27 + ci * 9 + k];
    }
    __syncthreads();

    float xv[4][27];
    #pragma unroll
    for (int k = 0; k < 4; ++k) {
        int pos = tid + k * 256, h = pos >> 5, w = pos & 31;
        #pragma unroll
        for (int kh = 0; kh < 3; ++kh) {
            #pragma unroll
            for (int kw = 0; kw < 3; ++kw) {
                #pragma unroll
                for (int ci = 0; ci < 3; ++ci) {
                    int ih = h + kh - 1, iw = w + kw - 1;
                    bool ok = (unsigned)ih < 32u && (unsigned)iw < 32u;
                    xv[k][(kh * 3 + kw) * 3 + ci] = ok ? xs[ci * 1024 + ih * 32 + iw] : 0.0f;
                }
            }
        }
    }
    int lane = tid & 63, wv = tid >> 6;
    for (int co = 0; co < 32; ++co) {
        #pragma clang fp contract(off)
        const float* wp = &wsh[co * 27];
        float a0 = 0.f, a1 = 0.f, a2 = 0.f, a3 = 0.f;
        #pragma unroll
        for (int j = 0; j < 27; ++j) {
            float wj = wp[j];
            a0 = __builtin_fmaf(xv[0][j], wj, a0);
            a1 = __builtin_fmaf(xv[1][j], wj, a1);
            a2 = __builtin_fmaf(xv[2][j], wj, a2);
            a3 = __builtin_fmaf(xv[3][j], wj, a3);
        }
        double y0 = a0, y1 = a1, y2 = a2, y3 = a3;
        double s  = (y0 + y1) + (y2 + y3);
        double s2 = (y0 * y0 + y1 * y1) + (y2 * y2 + y3 * y3);
        s = waveRed(s); s2 = waveRed(s2);
        if (lane == 0) { redS[wv][co] = s; redS2[wv][co] = s2; }
    }
    __syncthreads();
    if (tid < 32) {
        atomicAdd(&sum[co0 + tid], (redS[0][tid] + redS[1][tid]) + (redS[2][tid] + redS[3][tid]));
    } else if (tid < 64) {
        int c = tid - 32;
        atomicAdd(&sumsq[co0 + c], (redS2[0][c] + redS2[1][c]) + (redS2[2][c] + redS2[3][c]));
    }
}

__global__ void finalize_c0(const double* __restrict__ sum, const double* __restrict__ sumsq,
                            const float* __restrict__ g, const float* __restrict__ b,
                            double* __restrict__ M, double* __restrict__ A,
                            double* __restrict__ BB) {
    int c = threadIdx.x;    // 128
    double m = sum[c] / 262144.0;
    double var = sumsq[c] / 262144.0 - m * m;
    M[c]  = m;
    A[c]  = (double)g[c] / sqrt(var + 1e-5);
    BB[c] = (double)b[c];
}

// ---------------------------------------------------------------- conv0 pack
__global__ __launch_bounds__(256, 1) void conv0_pack3(const float* __restrict__ x,
                                                      const float* __restrict__ w0,
                                                      const double* __restrict__ M,
                                                      const double* __restrict__ A,
                                                      const double* __restrict__ BB,
                                                      u64* __restrict__ A0) {
    __shared__ float xs[3072];
    __shared__ float wsh[3456];
    __shared__ double msh[128], ash[128], bsh[128];
    int tid = threadIdx.x, n = blockIdx.x >> 2;
    int pos = ((blockIdx.x & 3) << 8) + tid;
    for (int i = tid; i < 3072; i += 256) xs[i] = x[n * 3072 + i];
    for (int i = tid; i < 3456; i += 256) {
        int co = i / 27, j = i % 27;    // tap-major
        int ci = j % 3, k = j / 3;
        wsh[i] = w0[co * 27 + ci * 9 + k];
    }
    if (tid < 128) { msh[tid] = M[tid]; ash[tid] = A[tid]; bsh[tid] = BB[tid]; }
    __syncthreads();

    int h = pos >> 5, w = pos & 31;
    float xv[27];
    #pragma unroll
    for (int kh = 0; kh < 3; ++kh) {
        #pragma unroll
        for (int kw = 0; kw < 3; ++kw) {
            #pragma unroll
            for (int ci = 0; ci < 3; ++ci) {
                int ih = h + kh - 1, iw = w + kw - 1;
                bool ok = (unsigned)ih < 32u && (unsigned)iw < 32u;
                xv[(kh * 3 + kw) * 3 + ci] = ok ? xs[ci * 1024 + ih * 32 + iw] : 0.0f;
            }
        }
    }
    u64 b0 = 0, b1 = 0;
    #pragma unroll 4
    for (int co = 0; co < 128; ++co) {
        #pragma clang fp contract(off)
        float acc = 0.f;
        const float* wp = &wsh[co * 27];
        #pragma unroll
        for (int j = 0; j < 27; ++j) acc = __builtin_fmaf(xv[j], wp[j], acc);
        double t = ash[co] * ((double)acc - msh[co]) + bsh[co];
        u64 bit = t > 0.0 ? 1ull : 0ull;
        if (co < 64) b0 |= bit << co; else b1 |= bit << (co - 64);
    }
    size_t p = (size_t)n * 1024 + pos;
    A0[p * 2] = b0; A0[p * 2 + 1] = b1;
}

// ---------------------------------------------------------------- weight bit-pack
__global__ __launch_bounds__(256) void pack_w(const float* __restrict__ w,
                                              u64* __restrict__ Wb, int Ci, int Co) {
    int widx = blockIdx.x * 4 + (threadIdx.x >> 6);
    int lane = threadIdx.x & 63;
    int CW = Ci >> 6;
    int co = widx % Co;
    int rest = widx / Co;
    int cw = rest % CW;
    int k = rest / CW;
    int kh = k / 3, kw = k % 3;
    int ci = (cw << 6) | lane;
    float v = w[((size_t)(co * Ci + ci) * 3 + kh) * 3 + kw];
    u64 m = __ballot(v > 0.0f);
    if (lane == 0) Wb[widx] = m;
}

// per-(tap,co) weight popcounts for mask-free boundary correction
__global__ __launch_bounds__(256) void wpop_k(const u64* __restrict__ Wb,
                                              int* __restrict__ P9, int CW, int CO) {
    int i = blockIdx.x * 256 + threadIdx.x;
    if (i >= 9 * CO) return;
    int k = i / CO, co = i - k * CO;
    int s = 0;
    for (int cw = 0; cw < CW; ++cw) s += __popcll(Wb[(size_t)(k * CW + cw) * CO + co]);
    P9[i] = s;
}

// ---------------------------------------------------------------- LDS-staged binary conv, 4 co per thread
// Block = one (n, ho) output row covering ALL of CO (4 co/thread).
// Activation rows staged once into LDS (zero row/col pad). Inner loop:
// u64-granularity sliding column window (broadcast ds_read_b64), each loaded
// word xor'd against 4 weight sets -> VALU:LDS ~6:1. q accumulators packed
// two-per-int (16-bit halves; max 4608 so no carry). Pad taps are zero words
// counted unconditionally, corrected via precomputed per-tap weight popcounts:
//   dot = 64*CW*nv + 2*sum_pad P9[tap] - 2*q
template <int CW, int CO, int HI, bool POOL, int COT>
__global__ __launch_bounds__(256, 3) void bconv2(const u64* __restrict__ A,
                                                 const u64* __restrict__ Wb,
                                                 const int* __restrict__ P9,
                                                 short* __restrict__ dots,
                                                 i64* __restrict__ sums) {
    constexpr int WI = HI;
    constexpr int HO = POOL ? HI / 2 : HI;
    constexpr int WO = POOL ? WI / 2 : WI;
    constexpr int NR = POOL ? 4 : 3;
    constexpr int NCOL = POOL ? 4 : 3;
    constexpr int CL = CO / COT;          // distinct co-lane slots
    constexpr int WSPLIT = 256 / CL;
    constexpr int WOT = WO / WSPLIT;
    constexpr int LROW = (WI + 2) * CW;
    constexpr int NWORD = NR * LROW;
    constexpr int NC = POOL ? 4 : 1;
    constexpr int QW = COT / 2;

    __shared__ alignas(16) u64 xs[NWORD];

    const int tid = threadIdx.x;
    const int bid = blockIdx.x;
    const int ho = bid % HO;
    const int n = bid / HO;
    const int cl = tid % CL;
    const int co0 = cl * COT;
    const int ws = tid / CL;
    const int wo0 = ws * WOT;
    const int hbase = POOL ? 2 * ho - 1 : ho - 1;
    const int c0 = POOL ? 2 * wo0 : wo0;

    // ---- stage rows (zero row/col padding) ----
    const u64* An = A + (size_t)n * HI * WI * CW;
    for (int i = tid; i < NWORD; i += 256) {
        int r = i / LROW;
        int rem = i - r * LROW;
        int c = rem / CW;
        int ch = rem - c * CW;
        int ih = hbase + r, iw = c - 1;
        u64 v = 0;
        if ((unsigned)ih < (unsigned)HI && (unsigned)iw < (unsigned)WI)
            v = An[(size_t)(ih * WI + iw) * CW + ch];
        xs[i] = v;
    }
    __syncthreads();

    int qp[WOT * NC][QW];
    #pragma unroll
    for (int i = 0; i < WOT * NC; ++i) {
        #pragma unroll
        for (int t = 0; t < QW; ++t) qp[i][t] = 0;
    }

    #pragma unroll 1
    for (int ch = 0; ch < CW; ++ch) {
        u64 wr[COT][9];
        #pragma unroll
        for (int k = 0; k < 9; ++k) {
            #pragma unroll
            for (int t2 = 0; t2 < QW; ++t2) {
                const ulonglong2 v =
                    *(const ulonglong2*)&Wb[(size_t)(k * CW + ch) * CO + co0 + 2 * t2];
                wr[2 * t2][k] = v.x; wr[2 * t2 + 1][k] = v.y;
            }
        }

        u64 wx[NR][NCOL];
        #pragma unroll
        for (int s = 0; s < 2; ++s) {
            #pragma unroll
            for (int r = 0; r < NR; ++r)
                wx[r][s] = xs[r * LROW + (c0 + s) * CW + ch];
        }

        #pragma unroll
        for (int j = 0; j < WOT; ++j) {
            if constexpr (!POOL) {
                #pragma unroll
                for (int r = 0; r < NR; ++r)
                    wx[r][(j + 2) % 3] = xs[r * LROW + (c0 + j + 2) * CW + ch];
                #pragma unroll
                for (int t = 0; t < COT; ++t) {
                    int qq = 0;
                    #pragma unroll
                    for (int kh = 0; kh < 3; ++kh) {
                        #pragma unroll
                        for (int kw = 0; kw < 3; ++kw)
                            qq += __popcll(wx[kh][(j + kw) % 3] ^ wr[t][kh * 3 + kw]);
                    }
                    qp[j][t >> 1] += (t & 1) ? (qq << 16) : qq;
                }
            } else {
                #pragma unroll
                for (int s = 2; s < 4; ++s) {
                    const int sl = (2 * j + s) & 3;
                    #pragma unroll
                    for (int r = 0; r < NR; ++r)
                        wx[r][sl] = xs[r * LROW + (c0 + 2 * j + s) * CW + ch];
                }
                #pragma unroll
                for (int py = 0; py < 2; ++py) {
                    #pragma unroll
                    for (int px = 0; px < 2; ++px) {
                        #pragma unroll
                        for (int t = 0; t < COT; ++t) {
                            int qq = 0;
                            #pragma unroll
                            for (int kh = 0; kh < 3; ++kh) {
                                #pragma unroll
                                for (int kw = 0; kw < 3; ++kw)
                                    qq += __popcll(wx[py + kh][(2 * j + px + kw) & 3]
                                                   ^ wr[t][kh * 3 + kw]);
                            }
                            qp[j * 4 + py * 2 + px][t >> 1] += (t & 1) ? (qq << 16) : qq;
                        }
                    }
                }
            }
        }
    }

    // ---- epilogue: pad correction, pooling max, store ----
    int Pt[COT][9];
    #pragma unroll
    for (int t = 0; t < COT; ++t) {
        #pragma unroll
        for (int k = 0; k < 9; ++k) Pt[t][k] = P9[k * CO + co0 + t];
    }

    int sa[COT], s2a[COT];
    #pragma unroll
    for (int t = 0; t < COT; ++t) { sa[t] = 0; s2a[t] = 0; }

    #pragma unroll
    for (int j = 0; j < WOT; ++j) {
        const int wo = wo0 + j;
        int best[COT];
        #pragma unroll
        for (int t = 0; t < COT; ++t) best[t] = -(1 << 30);

        if constexpr (!POOL) {
            const int rT = (ho == 0), rB = (ho == HI - 1);
            const int cL = (wo == 0), cR = (wo == WI - 1);
            const int nv = (3 - rT - rB) * (3 - cL - cR);
            #pragma unroll
            for (int t = 0; t < COT; ++t) {
                const int* P = Pt[t];
                const int pad = (rT ? P[0] + P[1] + P[2] : 0) + (rB ? P[6] + P[7] + P[8] : 0)
                              + (cL ? P[0] + P[3] + P[6] : 0) + (cR ? P[2] + P[5] + P[8] : 0)
                              - ((rT & cL) ? P[0] : 0) - ((rT & cR) ? P[2] : 0)
                              - ((rB & cL) ? P[6] : 0) - ((rB & cR) ? P[8] : 0);
                const int q = (t & 1) ? (int)(((unsigned)qp[j][t >> 1]) >> 16)
                                      : (qp[j][t >> 1] & 0xffff);
                best[t] = 64 * CW * nv + 2 * pad - 2 * q;
            }
        } else {
            #pragma unroll
            for (int py = 0; py < 2; ++py) {
                #pragma unroll
                for (int px = 0; px < 2; ++px) {
                    const int hc = 2 * ho + py, wc = 2 * wo + px;
                    const int rT = (hc == 0), rB = (hc == HI - 1);
                    const int cL = (wc == 0), cR = (wc == WI - 1);
                    const int nv = (3 - rT - rB) * (3 - cL - cR);
                    #pragma unroll
                    for (int t = 0; t < COT; ++t) {
                        const int* P = Pt[t];
                        const int pad = (rT ? P[0] + P[1] + P[2] : 0) + (rB ? P[6] + P[7] + P[8] : 0)
                                      + (cL ? P[0] + P[3] + P[6] : 0) + (cR ? P[2] + P[5] + P[8] : 0)
                                      - ((rT & cL) ? P[0] : 0) - ((rT & cR) ? P[2] : 0)
                                      - ((rB & cL) ? P[6] : 0) - ((rB & cR) ? P[8] : 0);
                        const int q = (t & 1) ? (int)(((unsigned)qp[j * 4 + py * 2 + px][t >> 1]) >> 16)
                                              : (qp[j * 4 + py * 2 + px][t >> 1] & 0xffff);
                        const int d = 64 * CW * nv + 2 * pad - 2 * q;
                        best[t] = d > best[t] ? d : best[t];
                    }
                }
            }
        }

        const size_t base = (size_t)((n * HO + ho) * WO + wo) * CO + co0;
        if constexpr (COT == 2) {
            int v = (int)((unsigned short)best[0] | ((unsigned)(unsigned short)best[1] << 16));
            *(int*)&dots[base] = v;
        } else {
            int v0 = (int)((unsigned short)best[0] | ((unsigned)(unsigned short)best[1] << 16));
            int v1 = (int)((unsigned short)best[2] | ((unsigned)(unsigned short)best[3] << 16));
            *(int2*)&dots[base] = make_int2(v0, v1);
        }
        #pragma unroll
        for (int t = 0; t < COT; ++t) { sa[t] += best[t]; s2a[t] += best[t] * best[t]; }
    }

    #pragma unroll
    for (int t = 0; t < COT; ++t) {
        atomicAdd((u64*)&sums[co0 + t], (u64)(i64)sa[t]);
        atomicAdd((u64*)&sums[CO + co0 + t], (u64)(i64)s2a[t]);
    }
}

__global__ void finalize_bn(const i64* __restrict__ sums,
                            const float* __restrict__ g, const float* __restrict__ b,
                            int CO, double cnt, double* __restrict__ M,
                            double* __restrict__ A, double* __restrict__ BB) {
    int c = blockIdx.x * blockDim.x + threadIdx.x;
    if (c >= CO) return;
    double m = (double)sums[c] / cnt;
    double var = (double)sums[CO + c] / cnt - m * m;
    M[c]  = m;
    A[c]  = (double)g[c] / sqrt(var + 1e-5);
    BB[c] = (double)b[c];
}

// ---------------------------------------------------------------- binarize + bit-pack
template <int CO>
__global__ __launch_bounds__(256) void binpack_k(const short* __restrict__ xin,
                                                 const double* __restrict__ M,
                                                 const double* __restrict__ A,
                                                 const double* __restrict__ BB,
                                                 u64* __restrict__ Ab) {
    constexpr int CWo = CO / 64;
    int widx = blockIdx.x * 4 + (threadIdx.x >> 6);
    int lane = threadIdx.x & 63;
    int w = widx & (CWo - 1);
    int p = widx / CWo;
    int c = (w << 6) | lane;
    double t = A[c] * ((double)xin[(size_t)p * CO + c] - M[c]) + BB[c];
    u64 m = __ballot(t > 0.0);
    if (lane == 0) Ab[widx] = m;
}

// ---------------------------------------------------------------- FC head
__global__ __launch_bounds__(256) void fc_k(const short* __restrict__ x5,
                                            const double* __restrict__ M,
                                            const double* __restrict__ A,
                                            const double* __restrict__ BB,
                                            const float* __restrict__ wfc,
                                            const float* __restrict__ bfc,
                                            float* __restrict__ out) {
    int n = blockIdx.x / 10, k = blockIdx.x % 10;
    double acc = 0.0;
    for (int i = threadIdx.x; i < 8192; i += 256) {
        int c = i >> 4, hw = i & 15, h = hw >> 2, ww = hw & 3;
        double t = A[c] * ((double)x5[(size_t)((n * 4 + h) * 4 + ww) * 512 + c] - M[c]) + BB[c];
        t = t < -1.0 ? -1.0 : (t > 1.0 ? 1.0 : t);
        acc += t * (double)wfc[(size_t)k * 8192 + i];
    }
    acc = waveRed(acc);
    __shared__ double sd[4];
    if ((threadIdx.x & 63) == 0) sd[threadIdx.x >> 6] = acc;
    __syncthreads();
    if (threadIdx.x == 0)
        out[n * 10 + k] = (float)(sd[0] + sd[1] + sd[2] + sd[3] + (double)bfc[k]);
}

// ---------------------------------------------------------------- launch
extern "C" void kernel_launch(void* const* d_in, const int* in_sizes, int n_in,
                              void* d_out, int out_size, void* d_ws, size_t ws_size,
                              hipStream_t stream) {
    (void)in_sizes; (void)n_in; (void)out_size; (void)ws_size;

    const float* x   = (const float*)d_in[0];
    const float* w0  = (const float*)d_in[1];
    const float* g0  = (const float*)d_in[2];
    const float* b0  = (const float*)d_in[3];
    const float* w1  = (const float*)d_in[4];
    const float* g1  = (const float*)d_in[5];
    const float* b1  = (const float*)d_in[6];
    const float* w2  = (const float*)d_in[7];
    const float* g2  = (const float*)d_in[8];
    const float* b2  = (const float*)d_in[9];
    const float* w3  = (const float*)d_in[10];
    const float* g3  = (const float*)d_in[11];
    const float* b3  = (const float*)d_in[12];
    const float* w4  = (const float*)d_in[13];
    const float* g4  = (const float*)d_in[14];
    const float* b4  = (const float*)d_in[15];
    const float* w5  = (const float*)d_in[16];
    const float* g5  = (const float*)d_in[17];
    const float* b5  = (const float*)d_in[18];
    const float* wfc = (const float*)d_in[19];
    const float* bfc = (const float*)d_in[20];
    float* out = (float*)d_out;

    // ---- workspace layout (~43.2 MB) ----
    char* ws = (char*)d_ws;
    double* sum0   = (double*)ws;                  // 128
    double* sumsq0 = sum0 + 128;                   // 128
    i64* isums = (i64*)(sumsq0 + 128);             // 5 layers * 1024
    // zero span: 2048 + 40960 = 43008 bytes
    int* P9 = (int*)(ws + 43008);                  // 18432 B scratch, rewritten per layer
    double* M  = (double*)(ws + 65536);            // 6*512
    double* A  = M + 3072;
    double* BB = A + 3072;
    char* p = ws + 65536 + 73728;
    u64* A0 = (u64*)p;  p += (size_t)262144 * 2 * 8;   // 4 MiB
    u64* A1 = (u64*)p;  p += (size_t)65536 * 2 * 8;    // 1 MiB
    u64* A2 = (u64*)p;  p += (size_t)65536 * 4 * 8;    // 2 MiB
    u64* A3 = (u64*)p;  p += (size_t)16384 * 4 * 8;    // 0.5 MiB
    u64* A4 = (u64*)p;  p += (size_t)16384 * 8 * 8;    // 1 MiB
    u64* Wb1 = (u64*)p; p += 2304 * 8;
    u64* Wb2 = (u64*)p; p += 4608 * 8;
    u64* Wb3 = (u64*)p; p += 9216 * 8;
    u64* Wb4 = (u64*)p; p += 18432 * 8;
    u64* Wb5 = (u64*)p; p += 36864 * 8;
    p = (char*)(((uintptr_t)p + 255) & ~(uintptr_t)255);
    short* dots = (short*)p;                       // max 65536*256*2 = 33.5 MB

    hipMemsetAsync(d_ws, 0, 43008, stream);

    // weight bit-packs
    pack_w<<<576,  256, 0, stream>>>(w1, Wb1, 128, 128);
    pack_w<<<1152, 256, 0, stream>>>(w2, Wb2, 128, 256);
    pack_w<<<2304, 256, 0, stream>>>(w3, Wb3, 256, 256);
    pack_w<<<4608, 256, 0, stream>>>(w4, Wb4, 256, 512);
    pack_w<<<9216, 256, 0, stream>>>(w5, Wb5, 512, 512);

    // conv0 (np-f32 FMA (kh,kw,ci)) + BN0 + pack
    conv0_sums3<<<dim3(4, 256), 256, 0, stream>>>(x, w0, sum0, sumsq0);
    finalize_c0<<<1, 128, 0, stream>>>(sum0, sumsq0, g0, b0, M, A, BB);
    conv0_pack3<<<1024, 256, 0, stream>>>(x, w0, M, A, BB, A0);

    // L1: 128->128 @32x32, pool -> 16x16
    wpop_k<<<5, 256, 0, stream>>>(Wb1, P9, 2, 128);
    bconv2<2, 128, 32, true, 4><<<4096, 256, 0, stream>>>(A0, Wb1, P9, dots, isums);
    finalize_bn<<<1, 128, 0, stream>>>(isums, g1, b1, 128, 65536.0, M + 512, A + 512, BB + 512);
    binpack_k<128><<<32768, 256, 0, stream>>>(dots, M + 512, A + 512, BB + 512, A1);

    // L2: 128->256 @16x16
    wpop_k<<<9, 256, 0, stream>>>(Wb2, P9, 2, 256);
    bconv2<2, 256, 16, false, 4><<<4096, 256, 0, stream>>>(A1, Wb2, P9, dots, isums + 1024);
    finalize_bn<<<1, 256, 0, stream>>>(isums + 1024, g2, b2, 256, 65536.0, M + 1024, A + 1024, BB + 1024);
    binpack_k<256><<<65536, 256, 0, stream>>>(dots, M + 1024, A + 1024, BB + 1024, A2);

    // L3: 256->256 @16x16, pool -> 8x8
    wpop_k<<<9, 256, 0, stream>>>(Wb3, P9, 4, 256);
    bconv2<4, 256, 16, true, 4><<<2048, 256, 0, stream>>>(A2, Wb3, P9, dots, isums + 2048);
    finalize_bn<<<1, 256, 0, stream>>>(isums + 2048, g3, b3, 256, 16384.0, M + 1536, A + 1536, BB + 1536);
    binpack_k<256><<<16384, 256, 0, stream>>>(dots, M + 1536, A + 1536, BB + 1536, A3);

    // L4: 256->512 @8x8
    wpop_k<<<18, 256, 0, stream>>>(Wb4, P9, 4, 512);
    bconv2<4, 512, 8, false, 4><<<2048, 256, 0, stream>>>(A3, Wb4, P9, dots, isums + 3072);
    finalize_bn<<<1, 512, 0, stream>>>(isums + 3072, g4, b4, 512, 16384.0, M + 2048, A + 2048, BB + 2048);
    binpack_k<512><<<32768, 256, 0, stream>>>(dots, M + 2048, A + 2048, BB + 2048, A4);

    // L5: 512->512 @8x8, pool -> 4x4
    wpop_k<<<18, 256, 0, stream>>>(Wb5, P9, 8, 512);
    bconv2<8, 512, 8, true, 4><<<1024, 256, 0, stream>>>(A4, Wb5, P9, dots, isums + 4096);
    finalize_bn<<<1, 512, 0, stream>>>(isums + 4096, g5, b5, 512, 4096.0, M + 2560, A + 2560, BB + 2560);

    // FC head
    fc_k<<<2560, 256, 0, stream>>>(dots, M + 2560, A + 2560, BB + 2560, wfc, bfc, out);
}

// Round 3
// 1877.092 us; speedup vs baseline: 3.1657x; 3.1657x over previous
//
#include <hip/hip_runtime.h>
#include <cstdint>
#include <cstddef>

using u64 = unsigned long long;
using i64 = long long;

#define DEVI __device__ __forceinline__

// ---------------------------------------------------------------- reductions
DEVI double waveRed(double v) {
    #pragma unroll
    for (int o = 32; o > 0; o >>= 1) v += __shfl_down(v, o, 64);
    return v;
}

// ---------------------------------------------------------------- conv0 stats (np-f32: FMA chain, (kh,kw,ci) order)
__global__ __launch_bounds__(256, 1) void conv0_sums3(const float* __restrict__ x,
                                                      const float* __restrict__ w0,
                                                      double* __restrict__ sum,
                                                      double* __restrict__ sumsq) {
    __shared__ float xs[3072];
    __shared__ float wsh[864];          // 32 co * 27, tap-major
    __shared__ double redS[4][32], redS2[4][32];
    int tid = threadIdx.x, n = blockIdx.y, co0 = blockIdx.x * 32;
    for (int i = tid; i < 3072; i += 256) xs[i] = x[n * 3072 + i];
    for (int i = tid; i < 864; i += 256) {
        int co = i / 27, j = i % 27;    // j = tap-major (kh*3+kw)*3 + ci
        int ci = j % 3, k = j / 3;
        wsh[i] = w0[(co0 + co) * 27 + ci * 9 + k];
    }
    __syncthreads();

    float xv[4][27];
    #pragma unroll
    for (int k = 0; k < 4; ++k) {
        int pos = tid + k * 256, h = pos >> 5, w = pos & 31;
        #pragma unroll
        for (int kh = 0; kh < 3; ++kh) {
            #pragma unroll
            for (int kw = 0; kw < 3; ++kw) {
                #pragma unroll
                for (int ci = 0; ci < 3; ++ci) {
                    int ih = h + kh - 1, iw = w + kw - 1;
                    bool ok = (unsigned)ih < 32u && (unsigned)iw < 32u;
                    xv[k][(kh * 3 + kw) * 3 + ci] = ok ? xs[ci * 1024 + ih * 32 + iw] : 0.0f;
                }
            }
        }
    }
    int lane = tid & 63, wv = tid >> 6;
    for (int co = 0; co < 32; ++co) {
        #pragma clang fp contract(off)
        const float* wp = &wsh[co * 27];
        float a0 = 0.f, a1 = 0.f, a2 = 0.f, a3 = 0.f;
        #pragma unroll
        for (int j = 0; j < 27; ++j) {
            float wj = wp[j];
            a0 = __builtin_fmaf(xv[0][j], wj, a0);
            a1 = __builtin_fmaf(xv[1][j], wj, a1);
            a2 = __builtin_fmaf(xv[2][j], wj, a2);
            a3 = __builtin_fmaf(xv[3][j], wj, a3);
        }
        double y0 = a0, y1 = a1, y2 = a2, y3 = a3;
        double s  = (y0 + y1) + (y2 + y3);
        double s2 = (y0 * y0 + y1 * y1) + (y2 * y2 + y3 * y3);
        s = waveRed(s); s2 = waveRed(s2);
        if (lane == 0) { redS[wv][co] = s; redS2[wv][co] = s2; }
    }
    __syncthreads();
    if (tid < 32) {
        atomicAdd(&sum[co0 + tid], (redS[0][tid] + redS[1][tid]) + (redS[2][tid] + redS[3][tid]));
    } else if (tid < 64) {
        int c = tid - 32;
        atomicAdd(&sumsq[co0 + c], (redS2[0][c] + redS2[1][c]) + (redS2[2][c] + redS2[3][c]));
    }
}

__global__ void finalize_c0(const double* __restrict__ sum, const double* __restrict__ sumsq,
                            const float* __restrict__ g, const float* __restrict__ b,
                            double* __restrict__ M, double* __restrict__ A,
                            double* __restrict__ BB) {
    int c = threadIdx.x;    // 128
    double m = sum[c] / 262144.0;
    double var = sumsq[c] / 262144.0 - m * m;
    M[c]  = m;
    A[c]  = (double)g[c] / sqrt(var + 1e-5);
    BB[c] = (double)b[c];
}

// ---------------------------------------------------------------- conv0 pack
__global__ __launch_bounds__(256, 1) void conv0_pack3(const float* __restrict__ x,
                                                      const float* __restrict__ w0,
                                                      const double* __restrict__ M,
                                                      const double* __restrict__ A,
                                                      const double* __restrict__ BB,
                                                      u64* __restrict__ A0) {
    __shared__ float xs[3072];
    __shared__ float wsh[3456];
    __shared__ double msh[128], ash[128], bsh[128];
    int tid = threadIdx.x, n = blockIdx.x >> 2;
    int pos = ((blockIdx.x & 3) << 8) + tid;
    for (int i = tid; i < 3072; i += 256) xs[i] = x[n * 3072 + i];
    for (int i = tid; i < 3456; i += 256) {
        int co = i / 27, j = i % 27;    // tap-major
        int ci = j % 3, k = j / 3;
        wsh[i] = w0[co * 27 + ci * 9 + k];
    }
    if (tid < 128) { msh[tid] = M[tid]; ash[tid] = A[tid]; bsh[tid] = BB[tid]; }
    __syncthreads();

    int h = pos >> 5, w = pos & 31;
    float xv[27];
    #pragma unroll
    for (int kh = 0; kh < 3; ++kh) {
        #pragma unroll
        for (int kw = 0; kw < 3; ++kw) {
            #pragma unroll
            for (int ci = 0; ci < 3; ++ci) {
                int ih = h + kh - 1, iw = w + kw - 1;
                bool ok = (unsigned)ih < 32u && (unsigned)iw < 32u;
                xv[(kh * 3 + kw) * 3 + ci] = ok ? xs[ci * 1024 + ih * 32 + iw] : 0.0f;
            }
        }
    }
    u64 b0 = 0, b1 = 0;
    #pragma unroll 4
    for (int co = 0; co < 128; ++co) {
        #pragma clang fp contract(off)
        float acc = 0.f;
        const float* wp = &wsh[co * 27];
        #pragma unroll
        for (int j = 0; j < 27; ++j) acc = __builtin_fmaf(xv[j], wp[j], acc);
        double t = ash[co] * ((double)acc - msh[co]) + bsh[co];
        u64 bit = t > 0.0 ? 1ull : 0ull;
        if (co < 64) b0 |= bit << co; else b1 |= bit << (co - 64);
    }
    size_t p = (size_t)n * 1024 + pos;
    A0[p * 2] = b0; A0[p * 2 + 1] = b1;
}

// ---------------------------------------------------------------- weight bit-pack
__global__ __launch_bounds__(256) void pack_w(const float* __restrict__ w,
                                              u64* __restrict__ Wb, int Ci, int Co) {
    int widx = blockIdx.x * 4 + (threadIdx.x >> 6);
    int lane = threadIdx.x & 63;
    int CW = Ci >> 6;
    int co = widx % Co;
    int rest = widx / Co;
    int cw = rest % CW;
    int k = rest / CW;
    int kh = k / 3, kw = k % 3;
    int ci = (cw << 6) | lane;
    float v = w[((size_t)(co * Ci + ci) * 3 + kh) * 3 + kw];
    u64 m = __ballot(v > 0.0f);
    if (lane == 0) Wb[widx] = m;
}

// per-(tap,co) weight popcounts for mask-free boundary correction
__global__ __launch_bounds__(256) void wpop_k(const u64* __restrict__ Wb,
                                              int* __restrict__ P9, int CW, int CO) {
    int i = blockIdx.x * 256 + threadIdx.x;
    if (i >= 9 * CO) return;
    int k = i / CO, co = i - k * CO;
    int s = 0;
    for (int cw = 0; cw < CW; ++cw) s += __popcll(Wb[(size_t)(k * CW + cw) * CO + co]);
    P9[i] = s;
}

// ---------------------------------------------------------------- LDS-staged binary conv, 2 co per thread
// Block = one (n, ho) output row covering ALL of CO (2 co/thread, wo-split).
// Activation rows staged once into LDS (zero row/col pad). Inner loop:
// u64-granularity sliding column window (broadcast ds_read_b64), each loaded
// word xor'd against 2 weight sets. All local arrays strictly constant-indexed
// under full unroll; no pointers into locals (R2 spill post-mortem). Pad taps
// are zero words counted unconditionally, corrected with precomputed per-tap
// weight popcounts P9:  dot = 64*CW*nv + 2*sum_pad P9[tap] - 2*q
template <int CW, int CO, int HI, bool POOL, int COT>
__global__ __launch_bounds__(256, 3) void bconv3(const u64* __restrict__ A,
                                                 const u64* __restrict__ Wb,
                                                 const int* __restrict__ P9,
                                                 short* __restrict__ dots,
                                                 i64* __restrict__ sums) {
    static_assert(COT == 2, "this kernel is tuned for 2 co per thread");
    constexpr int WI = HI;
    constexpr int HO = POOL ? HI / 2 : HI;
    constexpr int WO = POOL ? WI / 2 : WI;
    constexpr int NR = POOL ? 4 : 3;
    constexpr int NCOL = POOL ? 4 : 3;
    constexpr int CL = CO / COT;          // distinct co-lane slots
    constexpr int WSPLIT = 256 / CL;
    constexpr int WOT = WO / WSPLIT;
    constexpr int LROW = (WI + 2) * CW;
    constexpr int NWORD = NR * LROW;
    constexpr int NC = POOL ? 4 : 1;

    __shared__ alignas(16) u64 xs[NWORD];

    const int tid = threadIdx.x;
    const int bid = blockIdx.x;
    const int ho = bid % HO;
    const int n = bid / HO;
    const int cl = tid % CL;
    const int co0 = cl * COT;
    const int ws = tid / CL;
    const int wo0 = ws * WOT;
    const int hbase = POOL ? 2 * ho - 1 : ho - 1;
    const int c0 = POOL ? 2 * wo0 : wo0;

    // ---- stage rows (zero row/col padding) ----
    const u64* An = A + (size_t)n * HI * WI * CW;
    for (int i = tid; i < NWORD; i += 256) {
        int r = i / LROW;
        int rem = i - r * LROW;
        int c = rem / CW;
        int ch = rem - c * CW;
        int ih = hbase + r, iw = c - 1;
        u64 v = 0;
        if ((unsigned)ih < (unsigned)HI && (unsigned)iw < (unsigned)WI)
            v = An[(size_t)(ih * WI + iw) * CW + ch];
        xs[i] = v;
    }
    __syncthreads();

    int q[WOT * NC * COT];
    #pragma unroll
    for (int i = 0; i < WOT * NC * COT; ++i) q[i] = 0;

    #pragma unroll 1
    for (int ch = 0; ch < CW; ++ch) {
        // weights for the co-pair: one ulonglong2 per tap (coalesced across co)
        u64 wr0[9], wr1[9];
        #pragma unroll
        for (int k = 0; k < 9; ++k) {
            const ulonglong2 v = *(const ulonglong2*)&Wb[(size_t)(k * CW + ch) * CO + co0];
            wr0[k] = v.x; wr1[k] = v.y;
        }

        u64 wx[NR][NCOL];
        #pragma unroll
        for (int s = 0; s < 2; ++s) {
            #pragma unroll
            for (int r = 0; r < NR; ++r)
                wx[r][s] = xs[r * LROW + (c0 + s) * CW + ch];
        }

        #pragma unroll
        for (int j = 0; j < WOT; ++j) {
            if constexpr (!POOL) {
                #pragma unroll
                for (int r = 0; r < NR; ++r)
                    wx[r][(j + 2) % 3] = xs[r * LROW + (c0 + j + 2) * CW + ch];
                int q0 = 0, q1 = 0;
                #pragma unroll
                for (int kh = 0; kh < 3; ++kh) {
                    #pragma unroll
                    for (int kw = 0; kw < 3; ++kw) {
                        const u64 xv = wx[kh][(j + kw) % 3];
                        q0 += __popcll(xv ^ wr0[kh * 3 + kw]);
                        q1 += __popcll(xv ^ wr1[kh * 3 + kw]);
                    }
                }
                q[j * COT + 0] += q0;
                q[j * COT + 1] += q1;
            } else {
                #pragma unroll
                for (int s = 2; s < 4; ++s) {
                    const int sl = (2 * j + s) & 3;
                    #pragma unroll
                    for (int r = 0; r < NR; ++r)
                        wx[r][sl] = xs[r * LROW + (c0 + 2 * j + s) * CW + ch];
                }
                #pragma unroll
                for (int py = 0; py < 2; ++py) {
                    #pragma unroll
                    for (int px = 0; px < 2; ++px) {
                        int q0 = 0, q1 = 0;
                        #pragma unroll
                        for (int kh = 0; kh < 3; ++kh) {
                            #pragma unroll
                            for (int kw = 0; kw < 3; ++kw) {
                                const u64 xv = wx[py + kh][(2 * j + px + kw) & 3];
                                q0 += __popcll(xv ^ wr0[kh * 3 + kw]);
                                q1 += __popcll(xv ^ wr1[kh * 3 + kw]);
                            }
                        }
                        q[(j * 4 + py * 2 + px) * COT + 0] += q0;
                        q[(j * 4 + py * 2 + px) * COT + 1] += q1;
                    }
                }
            }
        }
    }

    // ---- epilogue: pad correction, pooling max, store ----
    int PT[COT][9];
    #pragma unroll
    for (int t = 0; t < COT; ++t) {
        #pragma unroll
        for (int k = 0; k < 9; ++k) PT[t][k] = P9[k * CO + co0 + t];
    }

    int sa[COT], s2a[COT];
    #pragma unroll
    for (int t = 0; t < COT; ++t) { sa[t] = 0; s2a[t] = 0; }

    #pragma unroll
    for (int j = 0; j < WOT; ++j) {
        const int wo = wo0 + j;
        int best[COT];
        #pragma unroll
        for (int t = 0; t < COT; ++t) best[t] = -(1 << 30);

        #pragma unroll
        for (int cand = 0; cand < NC; ++cand) {
            const int py = POOL ? (cand >> 1) : 0;
            const int px = POOL ? (cand & 1) : 0;
            const int hc = POOL ? 2 * ho + py : ho;
            const int wc = POOL ? 2 * wo + px : wo;
            const int rT = (hc == 0), rB = (hc == HI - 1);
            const int cL = (wc == 0), cR = (wc == WI - 1);
            const int nv = (3 - rT - rB) * (3 - cL - cR);
            #pragma unroll
            for (int t = 0; t < COT; ++t) {
                const int pad = (rT ? PT[t][0] + PT[t][1] + PT[t][2] : 0)
                              + (rB ? PT[t][6] + PT[t][7] + PT[t][8] : 0)
                              + (cL ? PT[t][0] + PT[t][3] + PT[t][6] : 0)
                              + (cR ? PT[t][2] + PT[t][5] + PT[t][8] : 0)
                              - ((rT & cL) ? PT[t][0] : 0) - ((rT & cR) ? PT[t][2] : 0)
                              - ((rB & cL) ? PT[t][6] : 0) - ((rB & cR) ? PT[t][8] : 0);
                const int d = 64 * CW * nv + 2 * pad - 2 * q[(j * NC + cand) * COT + t];
                best[t] = d > best[t] ? d : best[t];
            }
        }

        const size_t base = (size_t)((n * HO + ho) * WO + wo) * CO + co0;
        int v = (int)((unsigned short)best[0] | ((unsigned)(unsigned short)best[1] << 16));
        *(int*)&dots[base] = v;
        #pragma unroll
        for (int t = 0; t < COT; ++t) { sa[t] += best[t]; s2a[t] += best[t] * best[t]; }
    }

    #pragma unroll
    for (int t = 0; t < COT; ++t) {
        atomicAdd((u64*)&sums[co0 + t], (u64)(i64)sa[t]);
        atomicAdd((u64*)&sums[CO + co0 + t], (u64)(i64)s2a[t]);
    }
}

__global__ void finalize_bn(const i64* __restrict__ sums,
                            const float* __restrict__ g, const float* __restrict__ b,
                            int CO, double cnt, double* __restrict__ M,
                            double* __restrict__ A, double* __restrict__ BB) {
    int c = blockIdx.x * blockDim.x + threadIdx.x;
    if (c >= CO) return;
    double m = (double)sums[c] / cnt;
    double var = (double)sums[CO + c] / cnt - m * m;
    M[c]  = m;
    A[c]  = (double)g[c] / sqrt(var + 1e-5);
    BB[c] = (double)b[c];
}

// ---------------------------------------------------------------- binarize + bit-pack
template <int CO>
__global__ __launch_bounds__(256) void binpack_k(const short* __restrict__ xin,
                                                 const double* __restrict__ M,
                                                 const double* __restrict__ A,
                                                 const double* __restrict__ BB,
                                                 u64* __restrict__ Ab) {
    constexpr int CWo = CO / 64;
    int widx = blockIdx.x * 4 + (threadIdx.x >> 6);
    int lane = threadIdx.x & 63;
    int w = widx & (CWo - 1);
    int p = widx / CWo;
    int c = (w << 6) | lane;
    double t = A[c] * ((double)xin[(size_t)p * CO + c] - M[c]) + BB[c];
    u64 m = __ballot(t > 0.0);
    if (lane == 0) Ab[widx] = m;
}

// ---------------------------------------------------------------- FC head
__global__ __launch_bounds__(256) void fc_k(const short* __restrict__ x5,
                                            const double* __restrict__ M,
                                            const double* __restrict__ A,
                                            const double* __restrict__ BB,
                                            const float* __restrict__ wfc,
                                            const float* __restrict__ bfc,
                                            float* __restrict__ out) {
    int n = blockIdx.x / 10, k = blockIdx.x % 10;
    double acc = 0.0;
    for (int i = threadIdx.x; i < 8192; i += 256) {
        int c = i >> 4, hw = i & 15, h = hw >> 2, ww = hw & 3;
        double t = A[c] * ((double)x5[(size_t)((n * 4 + h) * 4 + ww) * 512 + c] - M[c]) + BB[c];
        t = t < -1.0 ? -1.0 : (t > 1.0 ? 1.0 : t);
        acc += t * (double)wfc[(size_t)k * 8192 + i];
    }
    acc = waveRed(acc);
    __shared__ double sd[4];
    if ((threadIdx.x & 63) == 0) sd[threadIdx.x >> 6] = acc;
    __syncthreads();
    if (threadIdx.x == 0)
        out[n * 10 + k] = (float)(sd[0] + sd[1] + sd[2] + sd[3] + (double)bfc[k]);
}

// ---------------------------------------------------------------- launch
extern "C" void kernel_launch(void* const* d_in, const int* in_sizes, int n_in,
                              void* d_out, int out_size, void* d_ws, size_t ws_size,
                              hipStream_t stream) {
    (void)in_sizes; (void)n_in; (void)out_size; (void)ws_size;

    const float* x   = (const float*)d_in[0];
    const float* w0  = (const float*)d_in[1];
    const float* g0  = (const float*)d_in[2];
    const float* b0  = (const float*)d_in[3];
    const float* w1  = (const float*)d_in[4];
    const float* g1  = (const float*)d_in[5];
    const float* b1  = (const float*)d_in[6];
    const float* w2  = (const float*)d_in[7];
    const float* g2  = (const float*)d_in[8];
    const float* b2  = (const float*)d_in[9];
    const float* w3  = (const float*)d_in[10];
    const float* g3  = (const float*)d_in[11];
    const float* b3  = (const float*)d_in[12];
    const float* w4  = (const float*)d_in[13];
    const float* g4  = (const float*)d_in[14];
    const float* b4  = (const float*)d_in[15];
    const float* w5  = (const float*)d_in[16];
    const float* g5  = (const float*)d_in[17];
    const float* b5  = (const float*)d_in[18];
    const float* wfc = (const float*)d_in[19];
    const float* bfc = (const float*)d_in[20];
    float* out = (float*)d_out;

    // ---- workspace layout (~43.2 MB) ----
    char* ws = (char*)d_ws;
    double* sum0   = (double*)ws;                  // 128
    double* sumsq0 = sum0 + 128;                   // 128
    i64* isums = (i64*)(sumsq0 + 128);             // 5 layers * 1024
    // zero span: 2048 + 40960 = 43008 bytes
    int* P9 = (int*)(ws + 43008);                  // 18432 B scratch, rewritten per layer
    double* M  = (double*)(ws + 65536);            // 6*512
    double* A  = M + 3072;
    double* BB = A + 3072;
    char* p = ws + 65536 + 73728;
    u64* A0 = (u64*)p;  p += (size_t)262144 * 2 * 8;   // 4 MiB
    u64* A1 = (u64*)p;  p += (size_t)65536 * 2 * 8;    // 1 MiB
    u64* A2 = (u64*)p;  p += (size_t)65536 * 4 * 8;    // 2 MiB
    u64* A3 = (u64*)p;  p += (size_t)16384 * 4 * 8;    // 0.5 MiB
    u64* A4 = (u64*)p;  p += (size_t)16384 * 8 * 8;    // 1 MiB
    u64* Wb1 = (u64*)p; p += 2304 * 8;
    u64* Wb2 = (u64*)p; p += 4608 * 8;
    u64* Wb3 = (u64*)p; p += 9216 * 8;
    u64* Wb4 = (u64*)p; p += 18432 * 8;
    u64* Wb5 = (u64*)p; p += 36864 * 8;
    p = (char*)(((uintptr_t)p + 255) & ~(uintptr_t)255);
    short* dots = (short*)p;                       // max 65536*256*2 = 33.5 MB

    hipMemsetAsync(d_ws, 0, 43008, stream);

    // weight bit-packs
    pack_w<<<576,  256, 0, stream>>>(w1, Wb1, 128, 128);
    pack_w<<<1152, 256, 0, stream>>>(w2, Wb2, 128, 256);
    pack_w<<<2304, 256, 0, stream>>>(w3, Wb3, 256, 256);
    pack_w<<<4608, 256, 0, stream>>>(w4, Wb4, 256, 512);
    pack_w<<<9216, 256, 0, stream>>>(w5, Wb5, 512, 512);

    // conv0 (np-f32 FMA (kh,kw,ci)) + BN0 + pack
    conv0_sums3<<<dim3(4, 256), 256, 0, stream>>>(x, w0, sum0, sumsq0);
    finalize_c0<<<1, 128, 0, stream>>>(sum0, sumsq0, g0, b0, M, A, BB);
    conv0_pack3<<<1024, 256, 0, stream>>>(x, w0, M, A, BB, A0);

    // L1: 128->128 @32x32, pool -> 16x16
    wpop_k<<<5, 256, 0, stream>>>(Wb1, P9, 2, 128);
    bconv3<2, 128, 32, true, 2><<<4096, 256, 0, stream>>>(A0, Wb1, P9, dots, isums);
    finalize_bn<<<1, 128, 0, stream>>>(isums, g1, b1, 128, 65536.0, M + 512, A + 512, BB + 512);
    binpack_k<128><<<32768, 256, 0, stream>>>(dots, M + 512, A + 512, BB + 512, A1);

    // L2: 128->256 @16x16
    wpop_k<<<9, 256, 0, stream>>>(Wb2, P9, 2, 256);
    bconv3<2, 256, 16, false, 2><<<4096, 256, 0, stream>>>(A1, Wb2, P9, dots, isums + 1024);
    finalize_bn<<<1, 256, 0, stream>>>(isums + 1024, g2, b2, 256, 65536.0, M + 1024, A + 1024, BB + 1024);
    binpack_k<256><<<65536, 256, 0, stream>>>(dots, M + 1024, A + 1024, BB + 1024, A2);

    // L3: 256->256 @16x16, pool -> 8x8
    wpop_k<<<9, 256, 0, stream>>>(Wb3, P9, 4, 256);
    bconv3<4, 256, 16, true, 2><<<2048, 256, 0, stream>>>(A2, Wb3, P9, dots, isums + 2048);
    finalize_bn<<<1, 256, 0, stream>>>(isums + 2048, g3, b3, 256, 16384.0, M + 1536, A + 1536, BB + 1536);
    binpack_k<256><<<16384, 256, 0, stream>>>(dots, M + 1536, A + 1536, BB + 1536, A3);

    // L4: 256->512 @8x8
    wpop_k<<<18, 256, 0, stream>>>(Wb4, P9, 4, 512);
    bconv3<4, 512, 8, false, 2><<<2048, 256, 0, stream>>>(A3, Wb4, P9, dots, isums + 3072);
    finalize_bn<<<1, 512, 0, stream>>>(isums + 3072, g4, b4, 512, 16384.0, M + 2048, A + 2048, BB + 2048);
    binpack_k<512><<<32768, 256, 0, stream>>>(dots, M + 2048, A + 2048, BB + 2048, A4);

    // L5: 512->512 @8x8, pool -> 4x4
    wpop_k<<<18, 256, 0, stream>>>(Wb5, P9, 8, 512);
    bconv3<8, 512, 8, true, 2><<<1024, 256, 0, stream>>>(A4, Wb5, P9, dots, isums + 4096);
    finalize_bn<<<1, 512, 0, stream>>>(isums + 4096, g5, b5, 512, 4096.0, M + 2560, A + 2560, BB + 2560);

    // FC head
    fc_k<<<2560, 256, 0, stream>>>(dots, M + 2560, A + 2560, BB + 2560, wfc, bfc, out);
}

// Round 4
// 1040.988 us; speedup vs baseline: 5.7083x; 1.8032x over previous
//
#include <hip/hip_runtime.h>
#include <cstdint>
#include <cstddef>

using u64 = unsigned long long;
using i64 = long long;

#define DEVI __device__ __forceinline__

// ---------------------------------------------------------------- reductions
DEVI double waveRed(double v) {
    #pragma unroll
    for (int o = 32; o > 0; o >>= 1) v += __shfl_down(v, o, 64);
    return v;
}

// ---------------------------------------------------------------- conv0 stats (np-f32: FMA chain, (kh,kw,ci) order)
__global__ __launch_bounds__(256, 1) void conv0_sums3(const float* __restrict__ x,
                                                      const float* __restrict__ w0,
                                                      double* __restrict__ sum,
                                                      double* __restrict__ sumsq) {
    __shared__ float xs[3072];
    __shared__ float wsh[864];          // 32 co * 27, tap-major
    __shared__ double redS[4][32], redS2[4][32];
    int tid = threadIdx.x, n = blockIdx.y, co0 = blockIdx.x * 32;
    for (int i = tid; i < 3072; i += 256) xs[i] = x[n * 3072 + i];
    for (int i = tid; i < 864; i += 256) {
        int co = i / 27, j = i % 27;    // j = tap-major (kh*3+kw)*3 + ci
        int ci = j % 3, k = j / 3;
        wsh[i] = w0[(co0 + co) * 27 + ci * 9 + k];
    }
    __syncthreads();

    float xv[4][27];
    #pragma unroll
    for (int k = 0; k < 4; ++k) {
        int pos = tid + k * 256, h = pos >> 5, w = pos & 31;
        #pragma unroll
        for (int kh = 0; kh < 3; ++kh) {
            #pragma unroll
            for (int kw = 0; kw < 3; ++kw) {
                #pragma unroll
                for (int ci = 0; ci < 3; ++ci) {
                    int ih = h + kh - 1, iw = w + kw - 1;
                    bool ok = (unsigned)ih < 32u && (unsigned)iw < 32u;
                    xv[k][(kh * 3 + kw) * 3 + ci] = ok ? xs[ci * 1024 + ih * 32 + iw] : 0.0f;
                }
            }
        }
    }
    int lane = tid & 63, wv = tid >> 6;
    for (int co = 0; co < 32; ++co) {
        #pragma clang fp contract(off)
        const float* wp = &wsh[co * 27];
        float a0 = 0.f, a1 = 0.f, a2 = 0.f, a3 = 0.f;
        #pragma unroll
        for (int j = 0; j < 27; ++j) {
            float wj = wp[j];
            a0 = __builtin_fmaf(xv[0][j], wj, a0);
            a1 = __builtin_fmaf(xv[1][j], wj, a1);
            a2 = __builtin_fmaf(xv[2][j], wj, a2);
            a3 = __builtin_fmaf(xv[3][j], wj, a3);
        }
        double y0 = a0, y1 = a1, y2 = a2, y3 = a3;
        double s  = (y0 + y1) + (y2 + y3);
        double s2 = (y0 * y0 + y1 * y1) + (y2 * y2 + y3 * y3);
        s = waveRed(s); s2 = waveRed(s2);
        if (lane == 0) { redS[wv][co] = s; redS2[wv][co] = s2; }
    }
    __syncthreads();
    if (tid < 32) {
        atomicAdd(&sum[co0 + tid], (redS[0][tid] + redS[1][tid]) + (redS[2][tid] + redS[3][tid]));
    } else if (tid < 64) {
        int c = tid - 32;
        atomicAdd(&sumsq[co0 + c], (redS2[0][c] + redS2[1][c]) + (redS2[2][c] + redS2[3][c]));
    }
}

__global__ void finalize_c0(const double* __restrict__ sum, const double* __restrict__ sumsq,
                            const float* __restrict__ g, const float* __restrict__ b,
                            double* __restrict__ M, double* __restrict__ A,
                            double* __restrict__ BB) {
    int c = threadIdx.x;    // 128
    double m = sum[c] / 262144.0;
    double var = sumsq[c] / 262144.0 - m * m;
    M[c]  = m;
    A[c]  = (double)g[c] / sqrt(var + 1e-5);
    BB[c] = (double)b[c];
}

// ---------------------------------------------------------------- conv0 pack
__global__ __launch_bounds__(256, 1) void conv0_pack3(const float* __restrict__ x,
                                                      const float* __restrict__ w0,
                                                      const double* __restrict__ M,
                                                      const double* __restrict__ A,
                                                      const double* __restrict__ BB,
                                                      u64* __restrict__ A0) {
    __shared__ float xs[3072];
    __shared__ float wsh[3456];
    __shared__ double msh[128], ash[128], bsh[128];
    int tid = threadIdx.x, n = blockIdx.x >> 2;
    int pos = ((blockIdx.x & 3) << 8) + tid;
    for (int i = tid; i < 3072; i += 256) xs[i] = x[n * 3072 + i];
    for (int i = tid; i < 3456; i += 256) {
        int co = i / 27, j = i % 27;    // tap-major
        int ci = j % 3, k = j / 3;
        wsh[i] = w0[co * 27 + ci * 9 + k];
    }
    if (tid < 128) { msh[tid] = M[tid]; ash[tid] = A[tid]; bsh[tid] = BB[tid]; }
    __syncthreads();

    int h = pos >> 5, w = pos & 31;
    float xv[27];
    #pragma unroll
    for (int kh = 0; kh < 3; ++kh) {
        #pragma unroll
        for (int kw = 0; kw < 3; ++kw) {
            #pragma unroll
            for (int ci = 0; ci < 3; ++ci) {
                int ih = h + kh - 1, iw = w + kw - 1;
                bool ok = (unsigned)ih < 32u && (unsigned)iw < 32u;
                xv[(kh * 3 + kw) * 3 + ci] = ok ? xs[ci * 1024 + ih * 32 + iw] : 0.0f;
            }
        }
    }
    u64 b0 = 0, b1 = 0;
    #pragma unroll 4
    for (int co = 0; co < 128; ++co) {
        #pragma clang fp contract(off)
        float acc = 0.f;
        const float* wp = &wsh[co * 27];
        #pragma unroll
        for (int j = 0; j < 27; ++j) acc = __builtin_fmaf(xv[j], wp[j], acc);
        double t = ash[co] * ((double)acc - msh[co]) + bsh[co];
        u64 bit = t > 0.0 ? 1ull : 0ull;
        if (co < 64) b0 |= bit << co; else b1 |= bit << (co - 64);
    }
    size_t p = (size_t)n * 1024 + pos;
    A0[p * 2] = b0; A0[p * 2 + 1] = b1;
}

// ---------------------------------------------------------------- weight bit-pack
__global__ __launch_bounds__(256) void pack_w(const float* __restrict__ w,
                                              u64* __restrict__ Wb, int Ci, int Co) {
    int widx = blockIdx.x * 4 + (threadIdx.x >> 6);
    int lane = threadIdx.x & 63;
    int CW = Ci >> 6;
    int co = widx % Co;
    int rest = widx / Co;
    int cw = rest % CW;
    int k = rest / CW;
    int kh = k / 3, kw = k % 3;
    int ci = (cw << 6) | lane;
    float v = w[((size_t)(co * Ci + ci) * 3 + kh) * 3 + kw];
    u64 m = __ballot(v > 0.0f);
    if (lane == 0) Wb[widx] = m;
}

// ---------------------------------------------------------------- bit binary conv (R0 proven kernel + split accumulators)
// Thread = (n, ho, co), co fastest -> all 64 lanes of a wave load the SAME
// activation address (broadcast L1 hit); weights resident in VGPRs.
// ILP fix vs R0: popcount accumulation split into 6 independent chains
// (per-kh x per-word pa[3]/pb[3], constant-indexed under full unroll) so the
// dependent-add chain is ~6x shorter. Same integer sum, bit-identical.
template <int CW, int CO, int HI, bool POOL>
__global__ __launch_bounds__(256, 2) void bconv_bits3(const u64* __restrict__ A,
                                                      const u64* __restrict__ Wb,
                                                      short* __restrict__ dots,
                                                      i64* __restrict__ sums) {
    constexpr int WI = HI;
    constexpr int HO = POOL ? HI / 2 : HI;
    constexpr int WO = HO;
    int gid = blockIdx.x * 256 + threadIdx.x;
    int co = gid % CO;
    int rest = gid / CO;
    int ho = rest % HO;
    int n = rest / HO;

    u64 wreg[9 * CW];
    #pragma unroll
    for (int t = 0; t < 9 * CW; ++t) wreg[t] = Wb[(size_t)t * CO + co];

    const u64* An = A + (size_t)n * HI * WI * CW;
    int s = 0, s2 = 0;
    #pragma unroll 2
    for (int wo = 0; wo < WO; ++wo) {
        int best = -(1 << 30);
        #pragma unroll
        for (int py = 0; py < (POOL ? 2 : 1); ++py) {
            #pragma unroll
            for (int px = 0; px < (POOL ? 2 : 1); ++px) {
                int hc = POOL ? 2 * ho + py : ho;
                int wc = POOL ? 2 * wo + px : wo;
                int pa[3], pb[3];
                #pragma unroll
                for (int k = 0; k < 3; ++k) { pa[k] = 0; pb[k] = 0; }
                int nv = 0;
                #pragma unroll
                for (int kh = 0; kh < 3; ++kh) {
                    int ih = hc + kh - 1;
                    if ((unsigned)ih >= (unsigned)HI) continue;
                    #pragma unroll
                    for (int kw = 0; kw < 3; ++kw) {
                        int iw = wc + kw - 1;
                        if ((unsigned)iw >= (unsigned)WI) continue;
                        const ulonglong2* ap =
                            (const ulonglong2*)(An + (size_t)(ih * WI + iw) * CW);
                        #pragma unroll
                        for (int cw = 0; cw < CW / 2; ++cw) {
                            ulonglong2 v = ap[cw];
                            pa[kh] += __popcll(v.x ^ wreg[(kh * 3 + kw) * CW + 2 * cw]);
                            pb[kh] += __popcll(v.y ^ wreg[(kh * 3 + kw) * CW + 2 * cw + 1]);
                        }
                        nv += CW * 64;
                    }
                }
                int pc = (pa[0] + pa[1] + pa[2]) + (pb[0] + pb[1] + pb[2]);
                int dot = nv - 2 * pc;
                best = dot > best ? dot : best;
            }
        }
        dots[(size_t)((n * HO + ho) * WO + wo) * CO + co] = (short)best;
        s += best;
        s2 += best * best;
    }
    atomicAdd((u64*)&sums[co], (u64)(i64)s);
    atomicAdd((u64*)&sums[CO + co], (u64)(i64)s2);
}

// ---------------------------------------------------------------- LDS-staged binary conv (R1 proven kernel, pooled layers)
// Block = one (n, ho) output row (x wo-split). 4 activation rows staged once
// into LDS (zero row/col pad); register sliding column window via broadcast
// ds_read_b128. Mask-free pad handling: pad taps are zero words counted
// unconditionally, corrected with per-tap weight popcounts accumulated in P[9].
template <int CW, int CO, int HI, bool POOL>
__global__ __launch_bounds__(256, 2) void bconv_lds(const u64* __restrict__ A,
                                                    const u64* __restrict__ Wb,
                                                    short* __restrict__ dots,
                                                    i64* __restrict__ sums) {
    constexpr int WI = HI;
    constexpr int HO = POOL ? HI / 2 : HI;
    constexpr int WO = POOL ? WI / 2 : WI;
    constexpr int NR = POOL ? 4 : 3;
    constexpr int NCOL = POOL ? 4 : 3;
    constexpr int CPB = (CO < 256) ? CO : 256;
    constexpr int BPR = CO / CPB;
    constexpr int WSPLIT = 256 / CPB;
    constexpr int WOT = WO / WSPLIT;
    constexpr int CH = CW / 2;
    constexpr int LROW = (WI + 2) * CW;
    constexpr int NWORD = NR * LROW;
    constexpr int NC = POOL ? 4 : 1;

    __shared__ alignas(16) u64 xs[NWORD];

    const int tid = threadIdx.x;
    const int bid = blockIdx.x;
    const int coh = bid % BPR;
    const int rest = bid / BPR;
    const int ho = rest % HO;
    const int n = rest / HO;
    const int co = coh * CPB + (tid % CPB);
    const int wo0 = (tid / CPB) * WOT;
    const int hbase = POOL ? 2 * ho - 1 : ho - 1;

    const u64* An = A + (size_t)n * HI * WI * CW;
    for (int i = tid; i < NWORD; i += 256) {
        int r = i / LROW;
        int rem = i - r * LROW;
        int c = rem / CW;
        int ch = rem - c * CW;
        int ih = hbase + r, iw = c - 1;
        u64 v = 0;
        if ((unsigned)ih < (unsigned)HI && (unsigned)iw < (unsigned)WI)
            v = An[(size_t)(ih * WI + iw) * CW + ch];
        xs[i] = v;
    }
    __syncthreads();

    int q[WOT * NC];
    #pragma unroll
    for (int i = 0; i < WOT * NC; ++i) q[i] = 0;
    int P[9];
    #pragma unroll
    for (int k = 0; k < 9; ++k) P[k] = 0;

    const int c0 = POOL ? 2 * wo0 : wo0;

    #pragma unroll 1
    for (int ch2 = 0; ch2 < CH; ++ch2) {
        u64 wa[9], wb[9];
        #pragma unroll
        for (int k = 0; k < 9; ++k) {
            wa[k] = Wb[(size_t)(k * CW + 2 * ch2) * CO + co];
            wb[k] = Wb[(size_t)(k * CW + 2 * ch2 + 1) * CO + co];
        }
        #pragma unroll
        for (int k = 0; k < 9; ++k) P[k] += __popcll(wa[k]) + __popcll(wb[k]);

        u64 wx[NR][NCOL], wy[NR][NCOL];
        #pragma unroll
        for (int s = 0; s < 2; ++s) {
            #pragma unroll
            for (int r = 0; r < NR; ++r) {
                const ulonglong2 v = *(const ulonglong2*)&xs[r * LROW + (c0 + s) * CW + 2 * ch2];
                wx[r][s] = v.x; wy[r][s] = v.y;
            }
        }
        #pragma unroll
        for (int j = 0; j < WOT; ++j) {
            if constexpr (!POOL) {
                #pragma unroll
                for (int r = 0; r < NR; ++r) {
                    const ulonglong2 v = *(const ulonglong2*)&xs[r * LROW + (c0 + j + 2) * CW + 2 * ch2];
                    wx[r][(j + 2) % 3] = v.x; wy[r][(j + 2) % 3] = v.y;
                }
                int qq = 0;
                #pragma unroll
                for (int kh = 0; kh < 3; ++kh) {
                    #pragma unroll
                    for (int kw = 0; kw < 3; ++kw) {
                        const int sl = (j + kw) % 3;
                        qq += __popcll(wx[kh][sl] ^ wa[kh * 3 + kw])
                            + __popcll(wy[kh][sl] ^ wb[kh * 3 + kw]);
                    }
                }
                q[j] += qq;
            } else {
                #pragma unroll
                for (int s = 2; s < 4; ++s) {
                    const int sl = (2 * j + s) & 3;
                    #pragma unroll
                    for (int r = 0; r < NR; ++r) {
                        const ulonglong2 v = *(const ulonglong2*)&xs[r * LROW + (c0 + 2 * j + s) * CW + 2 * ch2];
                        wx[r][sl] = v.x; wy[r][sl] = v.y;
                    }
                }
                #pragma unroll
                for (int py = 0; py < 2; ++py) {
                    #pragma unroll
                    for (int px = 0; px < 2; ++px) {
                        int qq = 0;
                        #pragma unroll
                        for (int kh = 0; kh < 3; ++kh) {
                            #pragma unroll
                            for (int kw = 0; kw < 3; ++kw) {
                                const int sl = (2 * j + px + kw) & 3;
                                qq += __popcll(wx[py + kh][sl] ^ wa[kh * 3 + kw])
                                    + __popcll(wy[py + kh][sl] ^ wb[kh * 3 + kw]);
                            }
                        }
                        q[j * 4 + py * 2 + px] += qq;
                    }
                }
            }
        }
    }

    const int prT = P[0] + P[1] + P[2];
    const int prB = P[6] + P[7] + P[8];
    const int pcL = P[0] + P[3] + P[6];
    const int pcR = P[2] + P[5] + P[8];
    const int k00 = P[0], k02 = P[2], k20 = P[6], k22 = P[8];

    int accS = 0, accS2 = 0;
    #pragma unroll
    for (int j = 0; j < WOT; ++j) {
        const int wo = wo0 + j;
        int best;
        if constexpr (!POOL) {
            const int rT = (ho == 0), rB = (ho == HI - 1);
            const int cL = (wo == 0), cR = (wo == WI - 1);
            const int nv = (3 - rT - rB) * (3 - cL - cR);
            const int pad = (rT ? prT : 0) + (rB ? prB : 0) + (cL ? pcL : 0) + (cR ? pcR : 0)
                          - ((rT & cL) ? k00 : 0) - ((rT & cR) ? k02 : 0)
                          - ((rB & cL) ? k20 : 0) - ((rB & cR) ? k22 : 0);
            best = 64 * CW * nv + 2 * pad - 2 * q[j];
        } else {
            best = -(1 << 30);
            #pragma unroll
            for (int py = 0; py < 2; ++py) {
                #pragma unroll
                for (int px = 0; px < 2; ++px) {
                    const int hc = 2 * ho + py, wc = 2 * wo + px;
                    const int rT = (hc == 0), rB = (hc == HI - 1);
                    const int cL = (wc == 0), cR = (wc == WI - 1);
                    const int nv = (3 - rT - rB) * (3 - cL - cR);
                    const int pad = (rT ? prT : 0) + (rB ? prB : 0) + (cL ? pcL : 0) + (cR ? pcR : 0)
                                  - ((rT & cL) ? k00 : 0) - ((rT & cR) ? k02 : 0)
                                  - ((rB & cL) ? k20 : 0) - ((rB & cR) ? k22 : 0);
                    const int d = 64 * CW * nv + 2 * pad - 2 * q[j * 4 + py * 2 + px];
                    best = d > best ? d : best;
                }
            }
        }
        dots[(size_t)((n * HO + ho) * WO + wo) * CO + co] = (short)best;
        accS += best;
        accS2 += best * best;
    }
    atomicAdd((u64*)&sums[co], (u64)(i64)accS);
    atomicAdd((u64*)&sums[CO + co], (u64)(i64)accS2);
}

__global__ void finalize_bn(const i64* __restrict__ sums,
                            const float* __restrict__ g, const float* __restrict__ b,
                            int CO, double cnt, double* __restrict__ M,
                            double* __restrict__ A, double* __restrict__ BB) {
    int c = blockIdx.x * blockDim.x + threadIdx.x;
    if (c >= CO) return;
    double m = (double)sums[c] / cnt;
    double var = (double)sums[CO + c] / cnt - m * m;
    M[c]  = m;
    A[c]  = (double)g[c] / sqrt(var + 1e-5);
    BB[c] = (double)b[c];
}

// ---------------------------------------------------------------- binarize + bit-pack
template <int CO>
__global__ __launch_bounds__(256) void binpack_k(const short* __restrict__ xin,
                                                 const double* __restrict__ M,
                                                 const double* __restrict__ A,
                                                 const double* __restrict__ BB,
                                                 u64* __restrict__ Ab) {
    constexpr int CWo = CO / 64;
    int widx = blockIdx.x * 4 + (threadIdx.x >> 6);
    int lane = threadIdx.x & 63;
    int w = widx & (CWo - 1);
    int p = widx / CWo;
    int c = (w << 6) | lane;
    double t = A[c] * ((double)xin[(size_t)p * CO + c] - M[c]) + BB[c];
    u64 m = __ballot(t > 0.0);
    if (lane == 0) Ab[widx] = m;
}

// ---------------------------------------------------------------- FC head
__global__ __launch_bounds__(256) void fc_k(const short* __restrict__ x5,
                                            const double* __restrict__ M,
                                            const double* __restrict__ A,
                                            const double* __restrict__ BB,
                                            const float* __restrict__ wfc,
                                            const float* __restrict__ bfc,
                                            float* __restrict__ out) {
    int n = blockIdx.x / 10, k = blockIdx.x % 10;
    double acc = 0.0;
    for (int i = threadIdx.x; i < 8192; i += 256) {
        int c = i >> 4, hw = i & 15, h = hw >> 2, ww = hw & 3;
        double t = A[c] * ((double)x5[(size_t)((n * 4 + h) * 4 + ww) * 512 + c] - M[c]) + BB[c];
        t = t < -1.0 ? -1.0 : (t > 1.0 ? 1.0 : t);
        acc += t * (double)wfc[(size_t)k * 8192 + i];
    }
    acc = waveRed(acc);
    __shared__ double sd[4];
    if ((threadIdx.x & 63) == 0) sd[threadIdx.x >> 6] = acc;
    __syncthreads();
    if (threadIdx.x == 0)
        out[n * 10 + k] = (float)(sd[0] + sd[1] + sd[2] + sd[3] + (double)bfc[k]);
}

// ---------------------------------------------------------------- launch
extern "C" void kernel_launch(void* const* d_in, const int* in_sizes, int n_in,
                              void* d_out, int out_size, void* d_ws, size_t ws_size,
                              hipStream_t stream) {
    (void)in_sizes; (void)n_in; (void)out_size; (void)ws_size;

    const float* x   = (const float*)d_in[0];
    const float* w0  = (const float*)d_in[1];
    const float* g0  = (const float*)d_in[2];
    const float* b0  = (const float*)d_in[3];
    const float* w1  = (const float*)d_in[4];
    const float* g1  = (const float*)d_in[5];
    const float* b1  = (const float*)d_in[6];
    const float* w2  = (const float*)d_in[7];
    const float* g2  = (const float*)d_in[8];
    const float* b2  = (const float*)d_in[9];
    const float* w3  = (const float*)d_in[10];
    const float* g3  = (const float*)d_in[11];
    const float* b3  = (const float*)d_in[12];
    const float* w4  = (const float*)d_in[13];
    const float* g4  = (const float*)d_in[14];
    const float* b4  = (const float*)d_in[15];
    const float* w5  = (const float*)d_in[16];
    const float* g5  = (const float*)d_in[17];
    const float* b5  = (const float*)d_in[18];
    const float* wfc = (const float*)d_in[19];
    const float* bfc = (const float*)d_in[20];
    float* out = (float*)d_out;

    // ---- workspace layout (~43.2 MB) ----
    char* ws = (char*)d_ws;
    double* sum0   = (double*)ws;                  // 128
    double* sumsq0 = sum0 + 128;                   // 128
    i64* isums = (i64*)(sumsq0 + 128);             // 5 layers * 1024
    // zero span: 2048 + 40960 = 43008 bytes
    double* M  = (double*)(ws + 65536);            // 6*512
    double* A  = M + 3072;
    double* BB = A + 3072;
    char* p = ws + 65536 + 73728;
    u64* A0 = (u64*)p;  p += (size_t)262144 * 2 * 8;   // 4 MiB
    u64* A1 = (u64*)p;  p += (size_t)65536 * 2 * 8;    // 1 MiB
    u64* A2 = (u64*)p;  p += (size_t)65536 * 4 * 8;    // 2 MiB
    u64* A3 = (u64*)p;  p += (size_t)16384 * 4 * 8;    // 0.5 MiB
    u64* A4 = (u64*)p;  p += (size_t)16384 * 8 * 8;    // 1 MiB
    u64* Wb1 = (u64*)p; p += 2304 * 8;
    u64* Wb2 = (u64*)p; p += 4608 * 8;
    u64* Wb3 = (u64*)p; p += 9216 * 8;
    u64* Wb4 = (u64*)p; p += 18432 * 8;
    u64* Wb5 = (u64*)p; p += 36864 * 8;
    p = (char*)(((uintptr_t)p + 255) & ~(uintptr_t)255);
    short* dots = (short*)p;                       // max 65536*256*2 = 33.5 MB

    hipMemsetAsync(d_ws, 0, 43008, stream);

    // weight bit-packs
    pack_w<<<576,  256, 0, stream>>>(w1, Wb1, 128, 128);
    pack_w<<<1152, 256, 0, stream>>>(w2, Wb2, 128, 256);
    pack_w<<<2304, 256, 0, stream>>>(w3, Wb3, 256, 256);
    pack_w<<<4608, 256, 0, stream>>>(w4, Wb4, 256, 512);
    pack_w<<<9216, 256, 0, stream>>>(w5, Wb5, 512, 512);

    // conv0 (np-f32 FMA (kh,kw,ci)) + BN0 + pack
    conv0_sums3<<<dim3(4, 256), 256, 0, stream>>>(x, w0, sum0, sumsq0);
    finalize_c0<<<1, 128, 0, stream>>>(sum0, sumsq0, g0, b0, M, A, BB);
    conv0_pack3<<<1024, 256, 0, stream>>>(x, w0, M, A, BB, A0);

    // L1: 128->128 @32x32, pool -> 16x16  (LDS window kernel, proven R1)
    bconv_lds<2, 128, 32, true><<<4096, 256, 0, stream>>>(A0, Wb1, dots, isums);
    finalize_bn<<<1, 128, 0, stream>>>(isums, g1, b1, 128, 65536.0, M + 512, A + 512, BB + 512);
    binpack_k<128><<<32768, 256, 0, stream>>>(dots, M + 512, A + 512, BB + 512, A1);

    // L2: 128->256 @16x16 (bits3 + split accumulators)
    bconv_bits3<2, 256, 16, false><<<4096, 256, 0, stream>>>(A1, Wb2, dots, isums + 1024);
    finalize_bn<<<1, 256, 0, stream>>>(isums + 1024, g2, b2, 256, 65536.0, M + 1024, A + 1024, BB + 1024);
    binpack_k<256><<<65536, 256, 0, stream>>>(dots, M + 1024, A + 1024, BB + 1024, A2);

    // L3: 256->256 @16x16, pool -> 8x8  (LDS window kernel, proven R1)
    bconv_lds<4, 256, 16, true><<<2048, 256, 0, stream>>>(A2, Wb3, dots, isums + 2048);
    finalize_bn<<<1, 256, 0, stream>>>(isums + 2048, g3, b3, 256, 16384.0, M + 1536, A + 1536, BB + 1536);
    binpack_k<256><<<16384, 256, 0, stream>>>(dots, M + 1536, A + 1536, BB + 1536, A3);

    // L4: 256->512 @8x8 (bits3 + split accumulators)
    bconv_bits3<4, 512, 8, false><<<4096, 256, 0, stream>>>(A3, Wb4, dots, isums + 3072);
    finalize_bn<<<1, 512, 0, stream>>>(isums + 3072, g4, b4, 512, 16384.0, M + 2048, A + 2048, BB + 2048);
    binpack_k<512><<<32768, 256, 0, stream>>>(dots, M + 2048, A + 2048, BB + 2048, A4);

    // L5: 512->512 @8x8, pool -> 4x4 (bits3 + split accumulators)
    bconv_bits3<8, 512, 8, true><<<2048, 256, 0, stream>>>(A4, Wb5, dots, isums + 4096);
    finalize_bn<<<1, 512, 0, stream>>>(isums + 4096, g5, b5, 512, 4096.0, M + 2560, A + 2560, BB + 2560);

    // FC head
    fc_k<<<2560, 256, 0, stream>>>(dots, M + 2560, A + 2560, BB + 2560, wfc, bfc, out);
}

// Round 5
// 1010.704 us; speedup vs baseline: 5.8793x; 1.0300x over previous
//
#include <hip/hip_runtime.h>
#include <cstdint>
#include <cstddef>

using u64 = unsigned long long;
using i64 = long long;

#define DEVI __device__ __forceinline__

// ---------------------------------------------------------------- reductions
DEVI double waveRed(double v) {
    #pragma unroll
    for (int o = 32; o > 0; o >>= 1) v += __shfl_down(v, o, 64);
    return v;
}

// ---------------------------------------------------------------- conv0 stats (np-f32: FMA chain, (kh,kw,ci) order)
__global__ __launch_bounds__(256, 1) void conv0_sums3(const float* __restrict__ x,
                                                      const float* __restrict__ w0,
                                                      double* __restrict__ sum,
                                                      double* __restrict__ sumsq) {
    __shared__ float xs[3072];
    __shared__ float wsh[864];          // 32 co * 27, tap-major
    __shared__ double redS[4][32], redS2[4][32];
    int tid = threadIdx.x, n = blockIdx.y, co0 = blockIdx.x * 32;
    for (int i = tid; i < 3072; i += 256) xs[i] = x[n * 3072 + i];
    for (int i = tid; i < 864; i += 256) {
        int co = i / 27, j = i % 27;    // j = tap-major (kh*3+kw)*3 + ci
        int ci = j % 3, k = j / 3;
        wsh[i] = w0[(co0 + co) * 27 + ci * 9 + k];
    }
    __syncthreads();

    float xv[4][27];
    #pragma unroll
    for (int k = 0; k < 4; ++k) {
        int pos = tid + k * 256, h = pos >> 5, w = pos & 31;
        #pragma unroll
        for (int kh = 0; kh < 3; ++kh) {
            #pragma unroll
            for (int kw = 0; kw < 3; ++kw) {
                #pragma unroll
                for (int ci = 0; ci < 3; ++ci) {
                    int ih = h + kh - 1, iw = w + kw - 1;
                    bool ok = (unsigned)ih < 32u && (unsigned)iw < 32u;
                    xv[k][(kh * 3 + kw) * 3 + ci] = ok ? xs[ci * 1024 + ih * 32 + iw] : 0.0f;
                }
            }
        }
    }
    int lane = tid & 63, wv = tid >> 6;
    for (int co = 0; co < 32; ++co) {
        #pragma clang fp contract(off)
        const float* wp = &wsh[co * 27];
        float a0 = 0.f, a1 = 0.f, a2 = 0.f, a3 = 0.f;
        #pragma unroll
        for (int j = 0; j < 27; ++j) {
            float wj = wp[j];
            a0 = __builtin_fmaf(xv[0][j], wj, a0);
            a1 = __builtin_fmaf(xv[1][j], wj, a1);
            a2 = __builtin_fmaf(xv[2][j], wj, a2);
            a3 = __builtin_fmaf(xv[3][j], wj, a3);
        }
        double y0 = a0, y1 = a1, y2 = a2, y3 = a3;
        double s  = (y0 + y1) + (y2 + y3);
        double s2 = (y0 * y0 + y1 * y1) + (y2 * y2 + y3 * y3);
        s = waveRed(s); s2 = waveRed(s2);
        if (lane == 0) { redS[wv][co] = s; redS2[wv][co] = s2; }
    }
    __syncthreads();
    if (tid < 32) {
        atomicAdd(&sum[co0 + tid], (redS[0][tid] + redS[1][tid]) + (redS[2][tid] + redS[3][tid]));
    } else if (tid < 64) {
        int c = tid - 32;
        atomicAdd(&sumsq[co0 + c], (redS2[0][c] + redS2[1][c]) + (redS2[2][c] + redS2[3][c]));
    }
}

__global__ void finalize_c0(const double* __restrict__ sum, const double* __restrict__ sumsq,
                            const float* __restrict__ g, const float* __restrict__ b,
                            double* __restrict__ M, double* __restrict__ A,
                            double* __restrict__ BB) {
    int c = threadIdx.x;    // 128
    double m = sum[c] / 262144.0;
    double var = sumsq[c] / 262144.0 - m * m;
    M[c]  = m;
    A[c]  = (double)g[c] / sqrt(var + 1e-5);
    BB[c] = (double)b[c];
}

// ---------------------------------------------------------------- conv0 pack
__global__ __launch_bounds__(256, 1) void conv0_pack3(const float* __restrict__ x,
                                                      const float* __restrict__ w0,
                                                      const double* __restrict__ M,
                                                      const double* __restrict__ A,
                                                      const double* __restrict__ BB,
                                                      u64* __restrict__ A0) {
    __shared__ float xs[3072];
    __shared__ float wsh[3456];
    __shared__ double msh[128], ash[128], bsh[128];
    int tid = threadIdx.x, n = blockIdx.x >> 2;
    int pos = ((blockIdx.x & 3) << 8) + tid;
    for (int i = tid; i < 3072; i += 256) xs[i] = x[n * 3072 + i];
    for (int i = tid; i < 3456; i += 256) {
        int co = i / 27, j = i % 27;    // tap-major
        int ci = j % 3, k = j / 3;
        wsh[i] = w0[co * 27 + ci * 9 + k];
    }
    if (tid < 128) { msh[tid] = M[tid]; ash[tid] = A[tid]; bsh[tid] = BB[tid]; }
    __syncthreads();

    int h = pos >> 5, w = pos & 31;
    float xv[27];
    #pragma unroll
    for (int kh = 0; kh < 3; ++kh) {
        #pragma unroll
        for (int kw = 0; kw < 3; ++kw) {
            #pragma unroll
            for (int ci = 0; ci < 3; ++ci) {
                int ih = h + kh - 1, iw = w + kw - 1;
                bool ok = (unsigned)ih < 32u && (unsigned)iw < 32u;
                xv[(kh * 3 + kw) * 3 + ci] = ok ? xs[ci * 1024 + ih * 32 + iw] : 0.0f;
            }
        }
    }
    u64 b0 = 0, b1 = 0;
    #pragma unroll 4
    for (int co = 0; co < 128; ++co) {
        #pragma clang fp contract(off)
        float acc = 0.f;
        const float* wp = &wsh[co * 27];
        #pragma unroll
        for (int j = 0; j < 27; ++j) acc = __builtin_fmaf(xv[j], wp[j], acc);
        double t = ash[co] * ((double)acc - msh[co]) + bsh[co];
        u64 bit = t > 0.0 ? 1ull : 0ull;
        if (co < 64) b0 |= bit << co; else b1 |= bit << (co - 64);
    }
    size_t p = (size_t)n * 1024 + pos;
    A0[p * 2] = b0; A0[p * 2 + 1] = b1;
}

// ---------------------------------------------------------------- weight bit-pack
__global__ __launch_bounds__(256) void pack_w(const float* __restrict__ w,
                                              u64* __restrict__ Wb, int Ci, int Co) {
    int widx = blockIdx.x * 4 + (threadIdx.x >> 6);
    int lane = threadIdx.x & 63;
    int CW = Ci >> 6;
    int co = widx % Co;
    int rest = widx / Co;
    int cw = rest % CW;
    int k = rest / CW;
    int kh = k / 3, kw = k % 3;
    int ci = (cw << 6) | lane;
    float v = w[((size_t)(co * Ci + ci) * 3 + kh) * 3 + kw];
    u64 m = __ballot(v > 0.0f);
    if (lane == 0) Wb[widx] = m;
}

// ---------------------------------------------------------------- bit binary conv (R0 proven kernel, EXACT)
template <int CW, int CO, int HI, bool POOL>
__global__ __launch_bounds__(256, 2) void bconv_bits3(const u64* __restrict__ A,
                                                      const u64* __restrict__ Wb,
                                                      short* __restrict__ dots,
                                                      i64* __restrict__ sums) {
    constexpr int WI = HI;
    constexpr int HO = POOL ? HI / 2 : HI;
    constexpr int WO = HO;
    int gid = blockIdx.x * 256 + threadIdx.x;
    int co = gid % CO;
    int rest = gid / CO;
    int ho = rest % HO;
    int n = rest / HO;

    u64 wreg[9 * CW];
    #pragma unroll
    for (int t = 0; t < 9 * CW; ++t) wreg[t] = Wb[(size_t)t * CO + co];

    const u64* An = A + (size_t)n * HI * WI * CW;
    int s = 0, s2 = 0;
    #pragma unroll 2
    for (int wo = 0; wo < WO; ++wo) {
        int best = -(1 << 30);
        #pragma unroll
        for (int py = 0; py < (POOL ? 2 : 1); ++py) {
            #pragma unroll
            for (int px = 0; px < (POOL ? 2 : 1); ++px) {
                int hc = POOL ? 2 * ho + py : ho;
                int wc = POOL ? 2 * wo + px : wo;
                int pc = 0, nv = 0;
                #pragma unroll
                for (int kh = 0; kh < 3; ++kh) {
                    int ih = hc + kh - 1;
                    if ((unsigned)ih >= (unsigned)HI) continue;
                    #pragma unroll
                    for (int kw = 0; kw < 3; ++kw) {
                        int iw = wc + kw - 1;
                        if ((unsigned)iw >= (unsigned)WI) continue;
                        const ulonglong2* ap =
                            (const ulonglong2*)(An + (size_t)(ih * WI + iw) * CW);
                        #pragma unroll
                        for (int cw = 0; cw < CW / 2; ++cw) {
                            ulonglong2 v = ap[cw];
                            pc += __popcll(v.x ^ wreg[(kh * 3 + kw) * CW + 2 * cw])
                                + __popcll(v.y ^ wreg[(kh * 3 + kw) * CW + 2 * cw + 1]);
                        }
                        nv += CW * 64;
                    }
                }
                int dot = nv - 2 * pc;
                best = dot > best ? dot : best;
            }
        }
        dots[(size_t)((n * HO + ho) * WO + wo) * CO + co] = (short)best;
        s += best;
        s2 += best * best;
    }
    atomicAdd((u64*)&sums[co], (u64)(i64)s);
    atomicAdd((u64*)&sums[CO + co], (u64)(i64)s2);
}

// ---------------------------------------------------------------- no-LDS sliding-window bconv (L2-class: CW=2, non-pool)
// Thread = (n, ho, co) with co = tid (CO == 256), block = one (n, ho) row.
// All 64 lanes of a wave share (n, ho) -> every activation load is a single
// broadcast L1 transaction. 3x3 column window slides across the row in
// registers: 3 new b128 loads per output instead of 9 (vs bits3). Full
// unroll, constant slot indices only (no dynamic local indexing).
// Borders: clamped addresses + (add & mask): row masks runtime, column masks
// compile-time (only j==0/kw==0 and j==WI-1/kw==2). Bit-identical math.
template <int CO, int HI>
__global__ __launch_bounds__(256, 2) void bconv_gslide2(const u64* __restrict__ A,
                                                        const u64* __restrict__ Wb,
                                                        short* __restrict__ dots,
                                                        i64* __restrict__ sums) {
    constexpr int WI = HI;
    constexpr int CW = 2;
    static_assert(CO == 256, "block covers all co");
    const int tid = threadIdx.x;
    const int bid = blockIdx.x;        // = n*HI + ho
    const int ho = bid % HI;
    const int n = bid / HI;
    const int co = tid;

    u64 wa[9], wb[9];
    #pragma unroll
    for (int k = 0; k < 9; ++k) {
        wa[k] = Wb[(size_t)(k * CW) * CO + co];
        wb[k] = Wb[(size_t)(k * CW + 1) * CO + co];
    }

    const u64* An = A + (size_t)n * HI * WI * CW;
    int rmask[3];
    const u64* rowp[3];
    #pragma unroll
    for (int r = 0; r < 3; ++r) {
        int ih = ho - 1 + r;
        rmask[r] = ((unsigned)ih < (unsigned)HI) ? -1 : 0;
        int ihc = ih < 0 ? 0 : (ih > HI - 1 ? HI - 1 : ih);
        rowp[r] = An + (size_t)ihc * WI * CW;
    }
    const int vr = 3 - (ho == 0) - (ho == HI - 1);

    u64 wx[3][3], wy[3][3];
    // preload window cols 0,1 (col c -> iw = c-1; c==0 is pad, clamped+masked)
    #pragma unroll
    for (int c = 0; c < 2; ++c) {
        const int iwc = (c - 1) < 0 ? 0 : (c - 1);
        #pragma unroll
        for (int r = 0; r < 3; ++r) {
            const ulonglong2 v = *(const ulonglong2*)(rowp[r] + (size_t)iwc * CW);
            wx[r][c] = v.x; wy[r][c] = v.y;
        }
    }

    int s = 0, s2 = 0;
    #pragma unroll
    for (int j = 0; j < WI; ++j) {
        // load window col j+2 (iw = j+1; OOB only at j == WI-1) -> slot (j+2)%3
        {
            const int iwc = (j + 1) > WI - 1 ? WI - 1 : (j + 1);
            const int sl = (j + 2) % 3;
            #pragma unroll
            for (int r = 0; r < 3; ++r) {
                const ulonglong2 v = *(const ulonglong2*)(rowp[r] + (size_t)iwc * CW);
                wx[r][sl] = v.x; wy[r][sl] = v.y;
            }
        }
        const int vc = 3 - (j == 0) - (j == WI - 1);
        int q = 0;
        #pragma unroll
        for (int kh = 0; kh < 3; ++kh) {
            #pragma unroll
            for (int kw = 0; kw < 3; ++kw) {
                const int c = j + kw;          // absolute window column
                const int sl = c % 3;
                if (c == 0 || c == WI + 1) continue;   // compile-time pad taps
                const int add = __popcll(wx[kh][sl] ^ wa[kh * 3 + kw])
                              + __popcll(wy[kh][sl] ^ wb[kh * 3 + kw]);
                q += add & rmask[kh];
            }
        }
        const int dot = vr * vc * CW * 64 - 2 * q;
        dots[(size_t)((n * HI + ho) * WI + j) * CO + co] = (short)dot;
        s += dot;
        s2 += dot * dot;
    }
    atomicAdd((u64*)&sums[co], (u64)(i64)s);
    atomicAdd((u64*)&sums[CO + co], (u64)(i64)s2);
}

// ---------------------------------------------------------------- LDS-staged binary conv (R1 proven kernel, pooled layers)
template <int CW, int CO, int HI, bool POOL>
__global__ __launch_bounds__(256, 2) void bconv_lds(const u64* __restrict__ A,
                                                    const u64* __restrict__ Wb,
                                                    short* __restrict__ dots,
                                                    i64* __restrict__ sums) {
    constexpr int WI = HI;
    constexpr int HO = POOL ? HI / 2 : HI;
    constexpr int WO = POOL ? WI / 2 : WI;
    constexpr int NR = POOL ? 4 : 3;
    constexpr int NCOL = POOL ? 4 : 3;
    constexpr int CPB = (CO < 256) ? CO : 256;
    constexpr int BPR = CO / CPB;
    constexpr int WSPLIT = 256 / CPB;
    constexpr int WOT = WO / WSPLIT;
    constexpr int CH = CW / 2;
    constexpr int LROW = (WI + 2) * CW;
    constexpr int NWORD = NR * LROW;
    constexpr int NC = POOL ? 4 : 1;

    __shared__ alignas(16) u64 xs[NWORD];

    const int tid = threadIdx.x;
    const int bid = blockIdx.x;
    const int coh = bid % BPR;
    const int rest = bid / BPR;
    const int ho = rest % HO;
    const int n = rest / HO;
    const int co = coh * CPB + (tid % CPB);
    const int wo0 = (tid / CPB) * WOT;
    const int hbase = POOL ? 2 * ho - 1 : ho - 1;

    const u64* An = A + (size_t)n * HI * WI * CW;
    for (int i = tid; i < NWORD; i += 256) {
        int r = i / LROW;
        int rem = i - r * LROW;
        int c = rem / CW;
        int ch = rem - c * CW;
        int ih = hbase + r, iw = c - 1;
        u64 v = 0;
        if ((unsigned)ih < (unsigned)HI && (unsigned)iw < (unsigned)WI)
            v = An[(size_t)(ih * WI + iw) * CW + ch];
        xs[i] = v;
    }
    __syncthreads();

    int q[WOT * NC];
    #pragma unroll
    for (int i = 0; i < WOT * NC; ++i) q[i] = 0;
    int P[9];
    #pragma unroll
    for (int k = 0; k < 9; ++k) P[k] = 0;

    const int c0 = POOL ? 2 * wo0 : wo0;

    #pragma unroll 1
    for (int ch2 = 0; ch2 < CH; ++ch2) {
        u64 wa[9], wb[9];
        #pragma unroll
        for (int k = 0; k < 9; ++k) {
            wa[k] = Wb[(size_t)(k * CW + 2 * ch2) * CO + co];
            wb[k] = Wb[(size_t)(k * CW + 2 * ch2 + 1) * CO + co];
        }
        #pragma unroll
        for (int k = 0; k < 9; ++k) P[k] += __popcll(wa[k]) + __popcll(wb[k]);

        u64 wx[NR][NCOL], wy[NR][NCOL];
        #pragma unroll
        for (int s = 0; s < 2; ++s) {
            #pragma unroll
            for (int r = 0; r < NR; ++r) {
                const ulonglong2 v = *(const ulonglong2*)&xs[r * LROW + (c0 + s) * CW + 2 * ch2];
                wx[r][s] = v.x; wy[r][s] = v.y;
            }
        }
        #pragma unroll
        for (int j = 0; j < WOT; ++j) {
            if constexpr (!POOL) {
                #pragma unroll
                for (int r = 0; r < NR; ++r) {
                    const ulonglong2 v = *(const ulonglong2*)&xs[r * LROW + (c0 + j + 2) * CW + 2 * ch2];
                    wx[r][(j + 2) % 3] = v.x; wy[r][(j + 2) % 3] = v.y;
                }
                int qq = 0;
                #pragma unroll
                for (int kh = 0; kh < 3; ++kh) {
                    #pragma unroll
                    for (int kw = 0; kw < 3; ++kw) {
                        const int sl = (j + kw) % 3;
                        qq += __popcll(wx[kh][sl] ^ wa[kh * 3 + kw])
                            + __popcll(wy[kh][sl] ^ wb[kh * 3 + kw]);
                    }
                }
                q[j] += qq;
            } else {
                #pragma unroll
                for (int s = 2; s < 4; ++s) {
                    const int sl = (2 * j + s) & 3;
                    #pragma unroll
                    for (int r = 0; r < NR; ++r) {
                        const ulonglong2 v = *(const ulonglong2*)&xs[r * LROW + (c0 + 2 * j + s) * CW + 2 * ch2];
                        wx[r][sl] = v.x; wy[r][sl] = v.y;
                    }
                }
                #pragma unroll
                for (int py = 0; py < 2; ++py) {
                    #pragma unroll
                    for (int px = 0; px < 2; ++px) {
                        int qq = 0;
                        #pragma unroll
                        for (int kh = 0; kh < 3; ++kh) {
                            #pragma unroll
                            for (int kw = 0; kw < 3; ++kw) {
                                const int sl = (2 * j + px + kw) & 3;
                                qq += __popcll(wx[py + kh][sl] ^ wa[kh * 3 + kw])
                                    + __popcll(wy[py + kh][sl] ^ wb[kh * 3 + kw]);
                            }
                        }
                        q[j * 4 + py * 2 + px] += qq;
                    }
                }
            }
        }
    }

    const int prT = P[0] + P[1] + P[2];
    const int prB = P[6] + P[7] + P[8];
    const int pcL = P[0] + P[3] + P[6];
    const int pcR = P[2] + P[5] + P[8];
    const int k00 = P[0], k02 = P[2], k20 = P[6], k22 = P[8];

    int accS = 0, accS2 = 0;
    #pragma unroll
    for (int j = 0; j < WOT; ++j) {
        const int wo = wo0 + j;
        int best;
        if constexpr (!POOL) {
            const int rT = (ho == 0), rB = (ho == HI - 1);
            const int cL = (wo == 0), cR = (wo == WI - 1);
            const int nv = (3 - rT - rB) * (3 - cL - cR);
            const int pad = (rT ? prT : 0) + (rB ? prB : 0) + (cL ? pcL : 0) + (cR ? pcR : 0)
                          - ((rT & cL) ? k00 : 0) - ((rT & cR) ? k02 : 0)
                          - ((rB & cL) ? k20 : 0) - ((rB & cR) ? k22 : 0);
            best = 64 * CW * nv + 2 * pad - 2 * q[j];
        } else {
            best = -(1 << 30);
            #pragma unroll
            for (int py = 0; py < 2; ++py) {
                #pragma unroll
                for (int px = 0; px < 2; ++px) {
                    const int hc = 2 * ho + py, wc = 2 * wo + px;
                    const int rT = (hc == 0), rB = (hc == HI - 1);
                    const int cL = (wc == 0), cR = (wc == WI - 1);
                    const int nv = (3 - rT - rB) * (3 - cL - cR);
                    const int pad = (rT ? prT : 0) + (rB ? prB : 0) + (cL ? pcL : 0) + (cR ? pcR : 0)
                                  - ((rT & cL) ? k00 : 0) - ((rT & cR) ? k02 : 0)
                                  - ((rB & cL) ? k20 : 0) - ((rB & cR) ? k22 : 0);
                    const int d = 64 * CW * nv + 2 * pad - 2 * q[j * 4 + py * 2 + px];
                    best = d > best ? d : best;
                }
            }
        }
        dots[(size_t)((n * HO + ho) * WO + wo) * CO + co] = (short)best;
        accS += best;
        accS2 += best * best;
    }
    atomicAdd((u64*)&sums[co], (u64)(i64)accS);
    atomicAdd((u64*)&sums[CO + co], (u64)(i64)accS2);
}

__global__ void finalize_bn(const i64* __restrict__ sums,
                            const float* __restrict__ g, const float* __restrict__ b,
                            int CO, double cnt, double* __restrict__ M,
                            double* __restrict__ A, double* __restrict__ BB) {
    int c = blockIdx.x * blockDim.x + threadIdx.x;
    if (c >= CO) return;
    double m = (double)sums[c] / cnt;
    double var = (double)sums[CO + c] / cnt - m * m;
    M[c]  = m;
    A[c]  = (double)g[c] / sqrt(var + 1e-5);
    BB[c] = (double)b[c];
}

// ---------------------------------------------------------------- binarize + bit-pack
template <int CO>
__global__ __launch_bounds__(256) void binpack_k(const short* __restrict__ xin,
                                                 const double* __restrict__ M,
                                                 const double* __restrict__ A,
                                                 const double* __restrict__ BB,
                                                 u64* __restrict__ Ab) {
    constexpr int CWo = CO / 64;
    int widx = blockIdx.x * 4 + (threadIdx.x >> 6);
    int lane = threadIdx.x & 63;
    int w = widx & (CWo - 1);
    int p = widx / CWo;
    int c = (w << 6) | lane;
    double t = A[c] * ((double)xin[(size_t)p * CO + c] - M[c]) + BB[c];
    u64 m = __ballot(t > 0.0);
    if (lane == 0) Ab[widx] = m;
}

// ---------------------------------------------------------------- FC head
__global__ __launch_bounds__(256) void fc_k(const short* __restrict__ x5,
                                            const double* __restrict__ M,
                                            const double* __restrict__ A,
                                            const double* __restrict__ BB,
                                            const float* __restrict__ wfc,
                                            const float* __restrict__ bfc,
                                            float* __restrict__ out) {
    int n = blockIdx.x / 10, k = blockIdx.x % 10;
    double acc = 0.0;
    for (int i = threadIdx.x; i < 8192; i += 256) {
        int c = i >> 4, hw = i & 15, h = hw >> 2, ww = hw & 3;
        double t = A[c] * ((double)x5[(size_t)((n * 4 + h) * 4 + ww) * 512 + c] - M[c]) + BB[c];
        t = t < -1.0 ? -1.0 : (t > 1.0 ? 1.0 : t);
        acc += t * (double)wfc[(size_t)k * 8192 + i];
    }
    acc = waveRed(acc);
    __shared__ double sd[4];
    if ((threadIdx.x & 63) == 0) sd[threadIdx.x >> 6] = acc;
    __syncthreads();
    if (threadIdx.x == 0)
        out[n * 10 + k] = (float)(sd[0] + sd[1] + sd[2] + sd[3] + (double)bfc[k]);
}

// ---------------------------------------------------------------- launch
extern "C" void kernel_launch(void* const* d_in, const int* in_sizes, int n_in,
                              void* d_out, int out_size, void* d_ws, size_t ws_size,
                              hipStream_t stream) {
    (void)in_sizes; (void)n_in; (void)out_size; (void)ws_size;

    const float* x   = (const float*)d_in[0];
    const float* w0  = (const float*)d_in[1];
    const float* g0  = (const float*)d_in[2];
    const float* b0  = (const float*)d_in[3];
    const float* w1  = (const float*)d_in[4];
    const float* g1  = (const float*)d_in[5];
    const float* b1  = (const float*)d_in[6];
    const float* w2  = (const float*)d_in[7];
    const float* g2  = (const float*)d_in[8];
    const float* b2  = (const float*)d_in[9];
    const float* w3  = (const float*)d_in[10];
    const float* g3  = (const float*)d_in[11];
    const float* b3  = (const float*)d_in[12];
    const float* w4  = (const float*)d_in[13];
    const float* g4  = (const float*)d_in[14];
    const float* b4  = (const float*)d_in[15];
    const float* w5  = (const float*)d_in[16];
    const float* g5  = (const float*)d_in[17];
    const float* b5  = (const float*)d_in[18];
    const float* wfc = (const float*)d_in[19];
    const float* bfc = (const float*)d_in[20];
    float* out = (float*)d_out;

    // ---- workspace layout (~43.2 MB) ----
    char* ws = (char*)d_ws;
    double* sum0   = (double*)ws;                  // 128
    double* sumsq0 = sum0 + 128;                   // 128
    i64* isums = (i64*)(sumsq0 + 128);             // 5 layers * 1024
    // zero span: 2048 + 40960 = 43008 bytes
    double* M  = (double*)(ws + 65536);            // 6*512
    double* A  = M + 3072;
    double* BB = A + 3072;
    char* p = ws + 65536 + 73728;
    u64* A0 = (u64*)p;  p += (size_t)262144 * 2 * 8;   // 4 MiB
    u64* A1 = (u64*)p;  p += (size_t)65536 * 2 * 8;    // 1 MiB
    u64* A2 = (u64*)p;  p += (size_t)65536 * 4 * 8;    // 2 MiB
    u64* A3 = (u64*)p;  p += (size_t)16384 * 4 * 8;    // 0.5 MiB
    u64* A4 = (u64*)p;  p += (size_t)16384 * 8 * 8;    // 1 MiB
    u64* Wb1 = (u64*)p; p += 2304 * 8;
    u64* Wb2 = (u64*)p; p += 4608 * 8;
    u64* Wb3 = (u64*)p; p += 9216 * 8;
    u64* Wb4 = (u64*)p; p += 18432 * 8;
    u64* Wb5 = (u64*)p; p += 36864 * 8;
    p = (char*)(((uintptr_t)p + 255) & ~(uintptr_t)255);
    short* dots = (short*)p;                       // max 65536*256*2 = 33.5 MB

    hipMemsetAsync(d_ws, 0, 43008, stream);

    // weight bit-packs
    pack_w<<<576,  256, 0, stream>>>(w1, Wb1, 128, 128);
    pack_w<<<1152, 256, 0, stream>>>(w2, Wb2, 128, 256);
    pack_w<<<2304, 256, 0, stream>>>(w3, Wb3, 256, 256);
    pack_w<<<4608, 256, 0, stream>>>(w4, Wb4, 256, 512);
    pack_w<<<9216, 256, 0, stream>>>(w5, Wb5, 512, 512);

    // conv0 (np-f32 FMA (kh,kw,ci)) + BN0 + pack
    conv0_sums3<<<dim3(4, 256), 256, 0, stream>>>(x, w0, sum0, sumsq0);
    finalize_c0<<<1, 128, 0, stream>>>(sum0, sumsq0, g0, b0, M, A, BB);
    conv0_pack3<<<1024, 256, 0, stream>>>(x, w0, M, A, BB, A0);

    // L1: 128->128 @32x32, pool -> 16x16  (LDS window kernel, proven R1)
    bconv_lds<2, 128, 32, true><<<4096, 256, 0, stream>>>(A0, Wb1, dots, isums);
    finalize_bn<<<1, 128, 0, stream>>>(isums, g1, b1, 128, 65536.0, M + 512, A + 512, BB + 512);
    binpack_k<128><<<32768, 256, 0, stream>>>(dots, M + 512, A + 512, BB + 512, A1);

    // L2: 128->256 @16x16 (no-LDS sliding-window kernel)
    bconv_gslide2<256, 16><<<4096, 256, 0, stream>>>(A1, Wb2, dots, isums + 1024);
    finalize_bn<<<1, 256, 0, stream>>>(isums + 1024, g2, b2, 256, 65536.0, M + 1024, A + 1024, BB + 1024);
    binpack_k<256><<<65536, 256, 0, stream>>>(dots, M + 1024, A + 1024, BB + 1024, A2);

    // L3: 256->256 @16x16, pool -> 8x8  (LDS window kernel, proven R1)
    bconv_lds<4, 256, 16, true><<<2048, 256, 0, stream>>>(A2, Wb3, dots, isums + 2048);
    finalize_bn<<<1, 256, 0, stream>>>(isums + 2048, g3, b3, 256, 16384.0, M + 1536, A + 1536, BB + 1536);
    binpack_k<256><<<16384, 256, 0, stream>>>(dots, M + 1536, A + 1536, BB + 1536, A3);

    // L4: 256->512 @8x8 (R0 bits3 exact)
    bconv_bits3<4, 512, 8, false><<<4096, 256, 0, stream>>>(A3, Wb4, dots, isums + 3072);
    finalize_bn<<<1, 512, 0, stream>>>(isums + 3072, g4, b4, 512, 16384.0, M + 2048, A + 2048, BB + 2048);
    binpack_k<512><<<32768, 256, 0, stream>>>(dots, M + 2048, A + 2048, BB + 2048, A4);

    // L5: 512->512 @8x8, pool -> 4x4 (R0 bits3 exact)
    bconv_bits3<8, 512, 8, true><<<2048, 256, 0, stream>>>(A4, Wb5, dots, isums + 4096);
    finalize_bn<<<1, 512, 0, stream>>>(isums + 4096, g5, b5, 512, 4096.0, M + 2560, A + 2560, BB + 2560);

    // FC head
    fc_k<<<2560, 256, 0, stream>>>(dots, M + 2560, A + 2560, BB + 2560, wfc, bfc, out);
}